// Round 3
// baseline (1144.108 us; speedup 1.0000x reference)
//
#include <hip/hip_runtime.h>
#include <hip/hip_bf16.h>

#define N_NODES 50000
#define NE      800000
#define IN_DIM  256
#define H_DIM   128
#define NL      2
#define NR      8
#define RD_DIM  16
#define CONF_W  0.5f
#define LN_EPS  1e-5f

// ---- order-preserving float<->uint encoding for atomicMax-based segment max.
// enc maps all real floats (incl. -inf) to values > 0, so a zeroed accumulator
// is a safe identity for max.
__device__ __forceinline__ unsigned enc_f(float f) {
    unsigned u = __float_as_uint(f);
    return (u & 0x80000000u) ? ~u : (u | 0x80000000u);
}
__device__ __forceinline__ float dec_f(unsigned e) {
    unsigned u = (e & 0x80000000u) ? (e ^ 0x80000000u) : ~e;
    return __uint_as_float(u);
}

// ---- zero the per-layer accumulators: outacc (N*H), m_enc (N), ssum (N)
__global__ void k_zero(float* __restrict__ outacc, unsigned* __restrict__ m_enc,
                       float* __restrict__ ssum) {
    int i = blockIdx.x * 256 + threadIdx.x;
    int stride = gridDim.x * 256;
    for (int j = i; j < N_NODES * H_DIM; j += stride) outacc[j] = 0.f;
    for (int j = i; j < N_NODES; j += stride) { m_enc[j] = 0u; ssum[j] = 0.f; }
}

// ---- tiny: rel_score[l][r] = rel_emb[l][r] . (W_rel[l] @ a_r[l])
__global__ void k_rel_score(const float* __restrict__ rel_emb,
                            const float* __restrict__ W_rel,
                            const float* __restrict__ att_vec,
                            float* __restrict__ rel_score) {
    __shared__ float wvec[NL][RD_DIM];
    int t = threadIdx.x;
    if (t < NL * RD_DIM) {
        int l = t / RD_DIM, d = t % RD_DIM;
        const float* wr = W_rel + ((size_t)l * RD_DIM + d) * H_DIM;
        const float* ar = att_vec + (size_t)l * 3 * H_DIM + 2 * H_DIM;
        float s = 0.f;
        for (int k = 0; k < H_DIM; ++k) s += wr[k] * ar[k];
        wvec[l][d] = s;
    }
    __syncthreads();
    if (t < NL * NR) {
        int l = t / NR, r = t % NR;
        const float* re = rel_emb + ((size_t)l * NR + r) * RD_DIM;
        float s = 0.f;
        for (int d = 0; d < RD_DIM; ++d) s += re[d] * wvec[l][d];
        rel_score[t] = s;
    }
}

// ---- fp32 tiled GEMM: C[M x 128] = A[M x K] @ W[K x 128] (+bias, relu)
// BM=64, BN=64, BK=16, 256 threads, 4x4 micro-tile per thread
template <int K, bool HASBIAS, bool RELU>
__global__ __launch_bounds__(256) void k_gemm(const float* __restrict__ A,
                                              const float* __restrict__ W,
                                              const float* __restrict__ bias,
                                              float* __restrict__ C, int M) {
    __shared__ float As[16][65];  // [k][m], padded to kill store bank conflicts
    __shared__ float Ws[16][64];  // [k][n]
    const int t = threadIdx.x;
    const int tx = t & 15, ty = t >> 4;
    const int m0 = blockIdx.x * 64, n0 = blockIdx.y * 64;

    float acc[4][4] = {};
    for (int k0 = 0; k0 < K; k0 += 16) {
#pragma unroll
        for (int i = 0; i < 4; ++i) {
            int idx = t + i * 256;
            int row = idx >> 4, col = idx & 15;
            int rm = m0 + row; rm = rm < M ? rm : M - 1;
            As[col][row] = A[(size_t)rm * K + k0 + col];
        }
#pragma unroll
        for (int i = 0; i < 4; ++i) {
            int idx = t + i * 256;
            int row = idx >> 6, col = idx & 63;
            Ws[row][col] = W[(size_t)(k0 + row) * H_DIM + n0 + col];
        }
        __syncthreads();
#pragma unroll
        for (int k = 0; k < 16; ++k) {
            float a[4], b[4];
#pragma unroll
            for (int j = 0; j < 4; ++j) a[j] = As[k][ty * 4 + j];
#pragma unroll
            for (int j = 0; j < 4; ++j) b[j] = Ws[k][tx * 4 + j];
#pragma unroll
            for (int ii = 0; ii < 4; ++ii)
#pragma unroll
                for (int jj = 0; jj < 4; ++jj) acc[ii][jj] += a[ii] * b[jj];
        }
        __syncthreads();
    }
#pragma unroll
    for (int ii = 0; ii < 4; ++ii) {
        int rm = m0 + ty * 4 + ii;
        if (rm < M) {
#pragma unroll
            for (int jj = 0; jj < 4; ++jj) {
                int cn = n0 + tx * 4 + jj;
                float v = acc[ii][jj];
                if (HASBIAS) v += bias[cn];
                if (RELU) v = fmaxf(v, 0.f);
                C[(size_t)rm * H_DIM + cn] = v;
            }
        }
    }
}

// ---- per-node attention score dots: dsc[n]=hm[n].a_d, ssc[n]=hm[n].a_s
__global__ void k_scores(const float* __restrict__ hm,
                         const float* __restrict__ att_vec_l,
                         float* __restrict__ dsc, float* __restrict__ ssc) {
    int wave = (blockIdx.x * blockDim.x + threadIdx.x) >> 6;
    int lane = threadIdx.x & 63;
    if (wave >= N_NODES) return;
    const float* row = hm + (size_t)wave * H_DIM;
    float v0 = row[lane], v1 = row[lane + 64];
    float d = v0 * att_vec_l[lane] + v1 * att_vec_l[lane + 64];
    float s = v0 * att_vec_l[H_DIM + lane] + v1 * att_vec_l[H_DIM + lane + 64];
    for (int off = 32; off; off >>= 1) {
        d += __shfl_down(d, off);
        s += __shfl_down(s, off);
    }
    if (lane == 0) { dsc[wave] = d; ssc[wave] = s; }
}

// ---- edge pass 1: logits + segment max (atomicMax on encoded uint)
__global__ void k_edge1(const int* __restrict__ srcv, const int* __restrict__ dstv,
                        const int* __restrict__ et, const float* __restrict__ ea,
                        const float* __restrict__ dsc, const float* __restrict__ ssc,
                        const float* __restrict__ rel_score_l,
                        float* __restrict__ e_out, unsigned* __restrict__ m_enc) {
    int i = blockIdx.x * 256 + threadIdx.x;
    if (i >= NE) return;
    int s = srcv[i], d = dstv[i];
    int t = et[i]; t = t < 0 ? 0 : (t > NR - 1 ? NR - 1 : t);
    float e = dsc[d] + ssc[s] + rel_score_l[t];
    e = (e > 0.f ? e : 0.2f * e) + CONF_W * logf(fmaxf(ea[i], 1e-6f));
    e_out[i] = e;
    atomicMax(m_enc + d, enc_f(e));
}

// ---- edge pass 2: exp(e - m[dst]) + segment sum
__global__ void k_edge2(const int* __restrict__ dstv, const float* __restrict__ e_in,
                        const unsigned* __restrict__ m_enc,
                        float* __restrict__ ex_out, float* __restrict__ ssum) {
    int i = blockIdx.x * 256 + threadIdx.x;
    if (i >= NE) return;
    int d = dstv[i];
    float ex = expf(e_in[i] - dec_f(m_enc[d]));
    ex_out[i] = ex;
    atomicAdd(ssum + d, ex);
}

// ---- edge pass 3: out[dst] += hm[src] * alpha (2 edges per 256-thread block)
__global__ __launch_bounds__(256) void k_aggregate(const int* __restrict__ srcv,
                                                   const int* __restrict__ dstv,
                                                   const float* __restrict__ ex,
                                                   const float* __restrict__ ssum,
                                                   const float* __restrict__ hm,
                                                   float* __restrict__ outacc) {
    int edge = blockIdx.x * 2 + (threadIdx.x >> 7);
    if (edge >= NE) return;
    int ch = threadIdx.x & 127;
    int s = srcv[edge], d = dstv[edge];
    float alpha = ex[edge] / ssum[d];
    atomicAdd(outacc + (size_t)d * H_DIM + ch, hm[(size_t)s * H_DIM + ch] * alpha);
}

// ---- residual + relu + layernorm (one wave per node, 2 channels/lane)
__global__ void k_ln(const float* __restrict__ h_in, const float* __restrict__ outacc,
                     const float* __restrict__ bias_l, const float* __restrict__ g,
                     const float* __restrict__ b, float* __restrict__ h_out) {
    int wave = (blockIdx.x * blockDim.x + threadIdx.x) >> 6;
    int lane = threadIdx.x & 63;
    if (wave >= N_NODES) return;
    size_t base = (size_t)wave * H_DIM;
    float o0 = outacc[base + lane] + bias_l[lane];
    float o1 = outacc[base + 64 + lane] + bias_l[64 + lane];
    float v0 = h_in[base + lane] + fmaxf(o0, 0.f);
    float v1 = h_in[base + 64 + lane] + fmaxf(o1, 0.f);
    float sum = v0 + v1;
    for (int off = 32; off; off >>= 1) sum += __shfl_xor(sum, off);
    float mu = sum * (1.f / H_DIM);
    float d0 = v0 - mu, d1 = v1 - mu;
    float vs = d0 * d0 + d1 * d1;
    for (int off = 32; off; off >>= 1) vs += __shfl_xor(vs, off);
    float inv = rsqrtf(vs * (1.f / H_DIM) + LN_EPS);
    h_out[base + lane] = d0 * inv * g[lane] + b[lane];
    h_out[base + 64 + lane] = d1 * inv * g[64 + lane] + b[64 + lane];
}

extern "C" void kernel_launch(void* const* d_in, const int* in_sizes, int n_in,
                              void* d_out, int out_size, void* d_ws, size_t ws_size,
                              hipStream_t stream) {
    const float* x         = (const float*)d_in[0];
    const int*   edge_index= (const int*)d_in[1];
    const int*   edge_type = (const int*)d_in[2];
    const float* edge_attr = (const float*)d_in[3];
    const float* W_in      = (const float*)d_in[4];
    const float* b_in      = (const float*)d_in[5];
    const float* W_msg     = (const float*)d_in[6];
    const float* rel_emb   = (const float*)d_in[7];
    const float* W_rel     = (const float*)d_in[8];
    const float* att_vec   = (const float*)d_in[9];
    const float* bias      = (const float*)d_in[10];
    const float* ln_g      = (const float*)d_in[11];
    const float* ln_b      = (const float*)d_in[12];
    float* out = (float*)d_out;

    // workspace layout (~81.7 MB total)
    char* w = (char*)d_ws;
    float* h_ws   = (float*)w; w += (size_t)N_NODES * H_DIM * 4;   // 25.6 MB
    float* hm     = (float*)w; w += (size_t)N_NODES * H_DIM * 4;   // 25.6 MB
    float* outacc = (float*)w; w += (size_t)N_NODES * H_DIM * 4;   // 25.6 MB
    float* e_ws   = (float*)w; w += (size_t)NE * 4;                //  3.2 MB
    float* dsc    = (float*)w; w += (size_t)N_NODES * 4;
    float* ssc    = (float*)w; w += (size_t)N_NODES * 4;
    unsigned* m_enc = (unsigned*)w; w += (size_t)N_NODES * 4;
    float* ssum   = (float*)w; w += (size_t)N_NODES * 4;
    float* rel_score = (float*)w; w += (size_t)NL * NR * 4;

    const int* srcv = edge_index;        // edge_index[0]
    const int* dstv = edge_index + NE;   // edge_index[1]

    k_rel_score<<<1, 256, 0, stream>>>(rel_emb, W_rel, att_vec, rel_score);
    k_gemm<IN_DIM, true, true><<<dim3((N_NODES + 63) / 64, 2), 256, 0, stream>>>(
        x, W_in, b_in, h_ws, N_NODES);

    for (int l = 0; l < NL; ++l) {
        k_gemm<H_DIM, false, false><<<dim3((N_NODES + 63) / 64, 2), 256, 0, stream>>>(
            h_ws, W_msg + (size_t)l * H_DIM * H_DIM, nullptr, hm, N_NODES);
        k_scores<<<(N_NODES * 64 + 255) / 256, 256, 0, stream>>>(
            hm, att_vec + (size_t)l * 3 * H_DIM, dsc, ssc);
        k_zero<<<2048, 256, 0, stream>>>(outacc, m_enc, ssum);
        k_edge1<<<(NE + 255) / 256, 256, 0, stream>>>(
            srcv, dstv, edge_type, edge_attr, dsc, ssc, rel_score + l * NR, e_ws, m_enc);
        k_edge2<<<(NE + 255) / 256, 256, 0, stream>>>(dstv, e_ws, m_enc, e_ws, ssum);
        k_aggregate<<<(NE + 1) / 2, 256, 0, stream>>>(srcv, dstv, e_ws, ssum, hm, outacc);
        k_ln<<<(N_NODES * 64 + 255) / 256, 256, 0, stream>>>(
            h_ws, outacc, bias + (size_t)l * H_DIM, ln_g + (size_t)l * H_DIM,
            ln_b + (size_t)l * H_DIM, (l == NL - 1) ? out : h_ws);
    }
}

// Round 4
// 555.965 us; speedup vs baseline: 2.0579x; 2.0579x over previous
//
#include <hip/hip_runtime.h>
#include <hip/hip_bf16.h>

#define N_NODES 50000
#define NE      800000
#define IN_DIM  256
#define H_DIM   128
#define NL      2
#define NR      8
#define RD_DIM  16
#define CONF_W  0.5f
#define LN_EPS  1e-5f

// ============ CSR build (dst is layer-invariant: build once per call) ============

__global__ void k_zero_counts(int* __restrict__ counts) {
    int i = blockIdx.x * 256 + threadIdx.x;
    if (i < N_NODES) counts[i] = 0;
}

// counts[dst]++ and remember each edge's rank within its dst segment
__global__ void k_count(const int* __restrict__ dstv, int* __restrict__ counts,
                        int* __restrict__ rank) {
    int i = blockIdx.x * 256 + threadIdx.x;
    if (i >= NE) return;
    rank[i] = atomicAdd(counts + dstv[i], 1);
}

// single-block exclusive scan over 50000 counts (1024 threads x 49-elem chunks)
__global__ __launch_bounds__(1024) void k_scan(const int* __restrict__ counts,
                                               int* __restrict__ offsets) {
    __shared__ int lsum[1024];
    const int t = threadIdx.x;
    const int CH = (N_NODES + 1023) / 1024;  // 49
    const int base = t * CH;
    int s = 0;
    for (int j = 0; j < CH; ++j) {
        int idx = base + j;
        if (idx < N_NODES) s += counts[idx];
    }
    lsum[t] = s;
    __syncthreads();
    for (int off = 1; off < 1024; off <<= 1) {
        int v = (t >= off) ? lsum[t - off] : 0;
        __syncthreads();
        lsum[t] += v;
        __syncthreads();
    }
    int run = (t == 0) ? 0 : lsum[t - 1];
    for (int j = 0; j < CH; ++j) {
        int idx = base + j;
        if (idx < N_NODES) { offsets[idx] = run; run += counts[idx]; }
    }
}

// scatter per-edge static data into dst-sorted order
__global__ void k_perm(const int* __restrict__ srcv, const int* __restrict__ dstv,
                       const int* __restrict__ et, const float* __restrict__ ea,
                       const int* __restrict__ offsets, const int* __restrict__ rank,
                       int* __restrict__ src_sorted, int* __restrict__ type_sorted,
                       float* __restrict__ lc_sorted) {
    int i = blockIdx.x * 256 + threadIdx.x;
    if (i >= NE) return;
    int p = offsets[dstv[i]] + rank[i];
    src_sorted[p] = srcv[i];
    int t = et[i]; t = t < 0 ? 0 : (t > NR - 1 ? NR - 1 : t);
    type_sorted[p] = t;
    lc_sorted[p] = CONF_W * logf(fmaxf(ea[i], 1e-6f));
}

// ============ tiny: rel_score[l][r] = rel_emb[l][r] . (W_rel[l] @ a_r[l]) ============
__global__ void k_rel_score(const float* __restrict__ rel_emb,
                            const float* __restrict__ W_rel,
                            const float* __restrict__ att_vec,
                            float* __restrict__ rel_score) {
    __shared__ float wvec[NL][RD_DIM];
    int t = threadIdx.x;
    if (t < NL * RD_DIM) {
        int l = t / RD_DIM, d = t % RD_DIM;
        const float* wr = W_rel + ((size_t)l * RD_DIM + d) * H_DIM;
        const float* ar = att_vec + (size_t)l * 3 * H_DIM + 2 * H_DIM;
        float s = 0.f;
        for (int k = 0; k < H_DIM; ++k) s += wr[k] * ar[k];
        wvec[l][d] = s;
    }
    __syncthreads();
    if (t < NL * NR) {
        int l = t / NR, r = t % NR;
        const float* re = rel_emb + ((size_t)l * NR + r) * RD_DIM;
        float s = 0.f;
        for (int d = 0; d < RD_DIM; ++d) s += re[d] * wvec[l][d];
        rel_score[t] = s;
    }
}

// ============ fp32 tiled GEMM: C[M x 128] = A[M x K] @ W[K x 128] ============
template <int K, bool HASBIAS, bool RELU>
__global__ __launch_bounds__(256) void k_gemm(const float* __restrict__ A,
                                              const float* __restrict__ W,
                                              const float* __restrict__ bias,
                                              float* __restrict__ C, int M) {
    __shared__ float As[16][65];
    __shared__ float Ws[16][64];
    const int t = threadIdx.x;
    const int tx = t & 15, ty = t >> 4;
    const int m0 = blockIdx.x * 64, n0 = blockIdx.y * 64;

    float acc[4][4] = {};
    for (int k0 = 0; k0 < K; k0 += 16) {
#pragma unroll
        for (int i = 0; i < 4; ++i) {
            int idx = t + i * 256;
            int row = idx >> 4, col = idx & 15;
            int rm = m0 + row; rm = rm < M ? rm : M - 1;
            As[col][row] = A[(size_t)rm * K + k0 + col];
        }
#pragma unroll
        for (int i = 0; i < 4; ++i) {
            int idx = t + i * 256;
            int row = idx >> 6, col = idx & 63;
            Ws[row][col] = W[(size_t)(k0 + row) * H_DIM + n0 + col];
        }
        __syncthreads();
#pragma unroll
        for (int k = 0; k < 16; ++k) {
            float a[4], b[4];
#pragma unroll
            for (int j = 0; j < 4; ++j) a[j] = As[k][ty * 4 + j];
#pragma unroll
            for (int j = 0; j < 4; ++j) b[j] = Ws[k][tx * 4 + j];
#pragma unroll
            for (int ii = 0; ii < 4; ++ii)
#pragma unroll
                for (int jj = 0; jj < 4; ++jj) acc[ii][jj] += a[ii] * b[jj];
        }
        __syncthreads();
    }
#pragma unroll
    for (int ii = 0; ii < 4; ++ii) {
        int rm = m0 + ty * 4 + ii;
        if (rm < M) {
#pragma unroll
            for (int jj = 0; jj < 4; ++jj) {
                int cn = n0 + tx * 4 + jj;
                float v = acc[ii][jj];
                if (HASBIAS) v += bias[cn];
                if (RELU) v = fmaxf(v, 0.f);
                C[(size_t)rm * H_DIM + cn] = v;
            }
        }
    }
}

// ============ per-node attention dots: dsc[n]=hm[n].a_d, ssc[n]=hm[n].a_s ============
__global__ void k_scores(const float* __restrict__ hm,
                         const float* __restrict__ att_vec_l,
                         float* __restrict__ dsc, float* __restrict__ ssc) {
    int wave = (blockIdx.x * blockDim.x + threadIdx.x) >> 6;
    int lane = threadIdx.x & 63;
    if (wave >= N_NODES) return;
    const float* row = hm + (size_t)wave * H_DIM;
    float v0 = row[lane], v1 = row[lane + 64];
    float d = v0 * att_vec_l[lane] + v1 * att_vec_l[lane + 64];
    float s = v0 * att_vec_l[H_DIM + lane] + v1 * att_vec_l[H_DIM + lane + 64];
    for (int off = 32; off; off >>= 1) {
        d += __shfl_down(d, off);
        s += __shfl_down(s, off);
    }
    if (lane == 0) { dsc[wave] = d; ssc[wave] = s; }
}

// ============ fused per-node: softmax over incoming edges + weighted gather
//              + bias + relu + residual + layernorm. One wave per node. ============
__global__ __launch_bounds__(256) void k_fused(
        const int* __restrict__ offsets, const int* __restrict__ counts,
        const int* __restrict__ src_sorted, const int* __restrict__ type_sorted,
        const float* __restrict__ lc_sorted,
        const float* __restrict__ dsc, const float* __restrict__ ssc,
        const float* __restrict__ rel_l,
        const float* __restrict__ hm, const float* __restrict__ h_in,
        const float* __restrict__ bias_l, const float* __restrict__ g,
        const float* __restrict__ b, float* __restrict__ h_out) {
    __shared__ float rel_s[NR];
    if (threadIdx.x < NR) rel_s[threadIdx.x] = rel_l[threadIdx.x];
    __syncthreads();

    const int wave = threadIdx.x >> 6, lane = threadIdx.x & 63;
    const int d = blockIdx.x * 4 + wave;   // grid covers exactly N_NODES
    if (d >= N_NODES) return;

    const int start = offsets[d];
    const int deg = counts[d];
    const float dsc_d = dsc[d];

    // pass 1: segment max (edge-parallel)
    float m = -1e30f;
    for (int j = lane; j < deg; j += 64) {
        int p = start + j;
        float e = dsc_d + ssc[src_sorted[p]] + rel_s[type_sorted[p]];
        e = (e > 0.f ? e : 0.2f * e) + lc_sorted[p];
        m = fmaxf(m, e);
    }
    for (int off = 32; off; off >>= 1) m = fmaxf(m, __shfl_xor(m, off));

    // pass 2: exp-sum (edge-parallel, recompute)
    float ssum = 0.f;
    for (int j = lane; j < deg; j += 64) {
        int p = start + j;
        float e = dsc_d + ssc[src_sorted[p]] + rel_s[type_sorted[p]];
        e = (e > 0.f ? e : 0.2f * e) + lc_sorted[p];
        ssum += expf(e - m);
    }
    for (int off = 32; off; off >>= 1) ssum += __shfl_xor(ssum, off);

    // pass 3: channel-parallel weighted gather (edges serial; all lanes
    // recompute the same scalar e — broadcast reads, trivial VALU cost)
    float2 acc = make_float2(0.f, 0.f);
    for (int k = 0; k < deg; ++k) {
        int p = start + k;
        int s = src_sorted[p];
        float e = dsc_d + ssc[s] + rel_s[type_sorted[p]];
        e = (e > 0.f ? e : 0.2f * e) + lc_sorted[p];
        float ex = expf(e - m);
        float2 row = *(const float2*)(hm + (size_t)s * H_DIM + 2 * lane);
        acc.x += ex * row.x;
        acc.y += ex * row.y;
    }

    const float inv = (deg > 0) ? 1.f / ssum : 0.f;
    const int c = 2 * lane;
    float2 bs = *(const float2*)(bias_l + c);
    float2 hi = *(const float2*)(h_in + (size_t)d * H_DIM + c);
    float v0 = hi.x + fmaxf(acc.x * inv + bs.x, 0.f);
    float v1 = hi.y + fmaxf(acc.y * inv + bs.y, 0.f);

    // layernorm over 128 channels (2 per lane)
    float sum = v0 + v1;
    for (int off = 32; off; off >>= 1) sum += __shfl_xor(sum, off);
    float mu = sum * (1.f / H_DIM);
    float d0 = v0 - mu, d1 = v1 - mu;
    float vs = d0 * d0 + d1 * d1;
    for (int off = 32; off; off >>= 1) vs += __shfl_xor(vs, off);
    float invstd = rsqrtf(vs * (1.f / H_DIM) + LN_EPS);
    float2 gg = *(const float2*)(g + c);
    float2 bb = *(const float2*)(b + c);
    float2 o;
    o.x = d0 * invstd * gg.x + bb.x;
    o.y = d1 * invstd * gg.y + bb.y;
    *(float2*)(h_out + (size_t)d * H_DIM + c) = o;
}

extern "C" void kernel_launch(void* const* d_in, const int* in_sizes, int n_in,
                              void* d_out, int out_size, void* d_ws, size_t ws_size,
                              hipStream_t stream) {
    const float* x         = (const float*)d_in[0];
    const int*   edge_index= (const int*)d_in[1];
    const int*   edge_type = (const int*)d_in[2];
    const float* edge_attr = (const float*)d_in[3];
    const float* W_in      = (const float*)d_in[4];
    const float* b_in      = (const float*)d_in[5];
    const float* W_msg     = (const float*)d_in[6];
    const float* rel_emb   = (const float*)d_in[7];
    const float* W_rel     = (const float*)d_in[8];
    const float* att_vec   = (const float*)d_in[9];
    const float* bias      = (const float*)d_in[10];
    const float* ln_g      = (const float*)d_in[11];
    const float* ln_b      = (const float*)d_in[12];
    float* out = (float*)d_out;

    // workspace layout (~65 MB)
    char* w = (char*)d_ws;
    float* h_ws       = (float*)w; w += (size_t)N_NODES * H_DIM * 4;  // 25.6 MB
    float* hm         = (float*)w; w += (size_t)N_NODES * H_DIM * 4;  // 25.6 MB
    int*   rank       = (int*)w;   w += (size_t)NE * 4;               //  3.2 MB
    int*   src_sorted = (int*)w;   w += (size_t)NE * 4;
    int*   type_sorted= (int*)w;   w += (size_t)NE * 4;
    float* lc_sorted  = (float*)w; w += (size_t)NE * 4;
    int*   counts     = (int*)w;   w += (size_t)N_NODES * 4;
    int*   offsets    = (int*)w;   w += (size_t)N_NODES * 4;
    float* dsc        = (float*)w; w += (size_t)N_NODES * 4;
    float* ssc        = (float*)w; w += (size_t)N_NODES * 4;
    float* rel_score  = (float*)w; w += (size_t)NL * NR * 4;

    const int* srcv = edge_index;        // edge_index[0]
    const int* dstv = edge_index + NE;   // edge_index[1]

    // ---- CSR build (once; dst is layer-invariant)
    k_zero_counts<<<(N_NODES + 255) / 256, 256, 0, stream>>>(counts);
    k_count<<<(NE + 255) / 256, 256, 0, stream>>>(dstv, counts, rank);
    k_scan<<<1, 1024, 0, stream>>>(counts, offsets);
    k_perm<<<(NE + 255) / 256, 256, 0, stream>>>(srcv, dstv, edge_type, edge_attr,
                                                 offsets, rank, src_sorted,
                                                 type_sorted, lc_sorted);
    k_rel_score<<<1, 256, 0, stream>>>(rel_emb, W_rel, att_vec, rel_score);

    k_gemm<IN_DIM, true, true><<<dim3((N_NODES + 63) / 64, 2), 256, 0, stream>>>(
        x, W_in, b_in, h_ws, N_NODES);

    for (int l = 0; l < NL; ++l) {
        k_gemm<H_DIM, false, false><<<dim3((N_NODES + 63) / 64, 2), 256, 0, stream>>>(
            h_ws, W_msg + (size_t)l * H_DIM * H_DIM, nullptr, hm, N_NODES);
        k_scores<<<(N_NODES * 64 + 255) / 256, 256, 0, stream>>>(
            hm, att_vec + (size_t)l * 3 * H_DIM, dsc, ssc);
        k_fused<<<(N_NODES + 3) / 4, 256, 0, stream>>>(
            offsets, counts, src_sorted, type_sorted, lc_sorted, dsc, ssc,
            rel_score + l * NR, hm, h_ws,
            bias + (size_t)l * H_DIM, ln_g + (size_t)l * H_DIM,
            ln_b + (size_t)l * H_DIM, (l == NL - 1) ? out : h_ws);
    }
}

// Round 6
// 461.523 us; speedup vs baseline: 2.4790x; 1.2046x over previous
//
#include <hip/hip_runtime.h>
#include <hip/hip_bf16.h>

#define N_NODES 50000
#define NE      800000
#define IN_DIM  256
#define H_DIM   128
#define NL      2
#define NR      8
#define RD_DIM  16
#define CONF_W  0.5f
#define LN_EPS  1e-5f

#define SCAN_CHUNK 1024
#define NB_SCAN    ((N_NODES + SCAN_CHUNK - 1) / SCAN_CHUNK)   // 49

// ============ CSR build (dst is layer-invariant: build once per call) ============

__global__ void k_zero_counts(int* __restrict__ counts) {
    int i = blockIdx.x * 256 + threadIdx.x;
    if (i < N_NODES) counts[i] = 0;
}

__global__ void k_count(const int* __restrict__ dstv, int* __restrict__ counts,
                        int* __restrict__ rank) {
    int i = blockIdx.x * 256 + threadIdx.x;
    if (i >= NE) return;
    rank[i] = atomicAdd(counts + dstv[i], 1);
}

// scan stage 1: per-block (1024 elems, 256 thr x 4 contiguous) total -> bsum[b]
__global__ __launch_bounds__(256) void k_scan1(const int* __restrict__ counts,
                                               int* __restrict__ bsum) {
    __shared__ int lsum[256];
    const int t = threadIdx.x, b = blockIdx.x;
    const int base = b * SCAN_CHUNK + t * 4;
    int s = 0;
#pragma unroll
    for (int j = 0; j < 4; ++j) {
        int idx = base + j;
        if (idx < N_NODES) s += counts[idx];
    }
    lsum[t] = s;
    __syncthreads();
    // tree-reduce
    for (int off = 128; off; off >>= 1) {
        if (t < off) lsum[t] += lsum[t + off];
        __syncthreads();
    }
    if (t == 0) bsum[b] = lsum[0];
}

// scan stage 2: one wave exclusive-scans the 49 block sums
__global__ void k_scan2(const int* __restrict__ bsum, int* __restrict__ bbase) {
    int lane = threadIdx.x & 63;
    int v = (lane < NB_SCAN) ? bsum[lane] : 0;
    int inc = v;
    for (int off = 1; off < 64; off <<= 1) {
        int tmp = __shfl_up(inc, off);
        if (lane >= off) inc += tmp;
    }
    if (lane < NB_SCAN) bbase[lane] = inc - v;   // exclusive
}

// scan stage 3: per-block exclusive scan + block base -> offsets
__global__ __launch_bounds__(256) void k_scan3(const int* __restrict__ counts,
                                               const int* __restrict__ bbase,
                                               int* __restrict__ offsets) {
    __shared__ int lsum[256];
    const int t = threadIdx.x, b = blockIdx.x;
    const int base = b * SCAN_CHUNK + t * 4;
    int c[4];
    int s = 0;
#pragma unroll
    for (int j = 0; j < 4; ++j) {
        int idx = base + j;
        c[j] = (idx < N_NODES) ? counts[idx] : 0;
        s += c[j];
    }
    lsum[t] = s;
    __syncthreads();
    // Hillis-Steele inclusive scan over thread sums
    for (int off = 1; off < 256; off <<= 1) {
        int v = (t >= off) ? lsum[t - off] : 0;
        __syncthreads();
        lsum[t] += v;
        __syncthreads();
    }
    int run = bbase[b] + lsum[t] - s;   // exclusive prefix for this thread
#pragma unroll
    for (int j = 0; j < 4; ++j) {
        int idx = base + j;
        if (idx < N_NODES) { offsets[idx] = run; run += c[j]; }
    }
}

// scatter per-edge static data into dst-sorted order
__global__ void k_perm(const int* __restrict__ srcv, const int* __restrict__ dstv,
                       const int* __restrict__ et, const float* __restrict__ ea,
                       const int* __restrict__ offsets, const int* __restrict__ rank,
                       int* __restrict__ src_sorted, int* __restrict__ type_sorted,
                       float* __restrict__ lc_sorted) {
    int i = blockIdx.x * 256 + threadIdx.x;
    if (i >= NE) return;
    int p = offsets[dstv[i]] + rank[i];
    src_sorted[p] = srcv[i];
    int t = et[i]; t = t < 0 ? 0 : (t > NR - 1 ? NR - 1 : t);
    type_sorted[p] = t;
    lc_sorted[p] = CONF_W * logf(fmaxf(ea[i], 1e-6f));
}

// ============ tiny: rel_score[l][r] = rel_emb[l][r] . (W_rel[l] @ a_r[l]) ============
__global__ void k_rel_score(const float* __restrict__ rel_emb,
                            const float* __restrict__ W_rel,
                            const float* __restrict__ att_vec,
                            float* __restrict__ rel_score) {
    __shared__ float wvec[NL][RD_DIM];
    int t = threadIdx.x;
    if (t < NL * RD_DIM) {
        int l = t / RD_DIM, d = t % RD_DIM;
        const float* wr = W_rel + ((size_t)l * RD_DIM + d) * H_DIM;
        const float* ar = att_vec + (size_t)l * 3 * H_DIM + 2 * H_DIM;
        float s = 0.f;
        for (int k = 0; k < H_DIM; ++k) s += wr[k] * ar[k];
        wvec[l][d] = s;
    }
    __syncthreads();
    if (t < NL * NR) {
        int l = t / NR, r = t % NR;
        const float* re = rel_emb + ((size_t)l * NR + r) * RD_DIM;
        float s = 0.f;
        for (int d = 0; d < RD_DIM; ++d) s += re[d] * wvec[l][d];
        rel_score[t] = s;
    }
}

// zero dsc/ssc before score-accumulating GEMM
__global__ void k_zero_scores(float* __restrict__ dsc, float* __restrict__ ssc) {
    int i = blockIdx.x * 256 + threadIdx.x;
    if (i < N_NODES) { dsc[i] = 0.f; ssc[i] = 0.f; }
}

// ============ fp32 tiled GEMM: C[M x 128] = A[M x K] @ W[K x 128] ============
// SCORES: also accumulate dsc[m] += C_row . a_d, ssc[m] += C_row . a_s (partial
// over this block's 64 columns, via 16-lane shfl reduce + one atomicAdd each).
template <int K, bool HASBIAS, bool RELU, bool SCORES>
__global__ __launch_bounds__(256) void k_gemm(const float* __restrict__ A,
                                              const float* __restrict__ W,
                                              const float* __restrict__ bias,
                                              float* __restrict__ C, int M,
                                              const float* __restrict__ att_vec_l,
                                              float* __restrict__ dsc,
                                              float* __restrict__ ssc) {
    __shared__ float As[16][65];
    __shared__ float Ws[16][64];
    const int t = threadIdx.x;
    const int tx = t & 15, ty = t >> 4;
    const int m0 = blockIdx.x * 64, n0 = blockIdx.y * 64;

    float acc[4][4] = {};
    for (int k0 = 0; k0 < K; k0 += 16) {
#pragma unroll
        for (int i = 0; i < 4; ++i) {
            int idx = t + i * 256;
            int row = idx >> 4, col = idx & 15;
            int rm = m0 + row; rm = rm < M ? rm : M - 1;
            As[col][row] = A[(size_t)rm * K + k0 + col];
        }
#pragma unroll
        for (int i = 0; i < 4; ++i) {
            int idx = t + i * 256;
            int row = idx >> 6, col = idx & 63;
            Ws[row][col] = W[(size_t)(k0 + row) * H_DIM + n0 + col];
        }
        __syncthreads();
#pragma unroll
        for (int k = 0; k < 16; ++k) {
            float a[4], b[4];
#pragma unroll
            for (int j = 0; j < 4; ++j) a[j] = As[k][ty * 4 + j];
#pragma unroll
            for (int j = 0; j < 4; ++j) b[j] = Ws[k][tx * 4 + j];
#pragma unroll
            for (int ii = 0; ii < 4; ++ii)
#pragma unroll
                for (int jj = 0; jj < 4; ++jj) acc[ii][jj] += a[ii] * b[jj];
        }
        __syncthreads();
    }

    float av[4], asv[4];
    if (SCORES) {
#pragma unroll
        for (int jj = 0; jj < 4; ++jj) {
            int cn = n0 + tx * 4 + jj;
            av[jj]  = att_vec_l[cn];
            asv[jj] = att_vec_l[H_DIM + cn];
        }
    }

#pragma unroll
    for (int ii = 0; ii < 4; ++ii) {
        int rm = m0 + ty * 4 + ii;
        bool valid = rm < M;
        if (valid) {
#pragma unroll
            for (int jj = 0; jj < 4; ++jj) {
                int cn = n0 + tx * 4 + jj;
                float v = acc[ii][jj];
                if (HASBIAS) v += bias[cn];
                if (RELU) v = fmaxf(v, 0.f);
                C[(size_t)rm * H_DIM + cn] = v;
            }
        }
        if (SCORES) {
            float pd = 0.f, ps = 0.f;
#pragma unroll
            for (int jj = 0; jj < 4; ++jj) {
                pd += acc[ii][jj] * av[jj];
                ps += acc[ii][jj] * asv[jj];
            }
            // reduce across the 16 lanes sharing this row (tx dimension)
#pragma unroll
            for (int off = 8; off; off >>= 1) {
                pd += __shfl_xor(pd, off);
                ps += __shfl_xor(ps, off);
            }
            if (tx == 0 && valid) {
                atomicAdd(dsc + rm, pd);
                atomicAdd(ssc + rm, ps);
            }
        }
    }
}

// ============ fused per-node: online softmax over incoming edges + weighted
//              gather + bias + relu + residual + layernorm. One wave per node. ====
__global__ __launch_bounds__(256) void k_fused(
        const int* __restrict__ offsets, const int* __restrict__ counts,
        const int* __restrict__ src_sorted, const int* __restrict__ type_sorted,
        const float* __restrict__ lc_sorted,
        const float* __restrict__ dsc, const float* __restrict__ ssc,
        const float* __restrict__ rel_l,
        const float* __restrict__ hm, const float* __restrict__ h_in,
        const float* __restrict__ bias_l, const float* __restrict__ g,
        const float* __restrict__ b, float* __restrict__ h_out) {
    __shared__ float rel_s[NR];
    if (threadIdx.x < NR) rel_s[threadIdx.x] = rel_l[threadIdx.x];
    __syncthreads();

    const int wave = threadIdx.x >> 6, lane = threadIdx.x & 63;
    const int d = blockIdx.x * 4 + wave;
    if (d >= N_NODES) return;

    const int start = offsets[d];
    const int deg = counts[d];
    const float dsc_d = dsc[d];

    // single online pass: per-lane (m_l, s_l), then cross-lane merge
    float m_l = -1e30f, s_l = 0.f;
    for (int j = lane; j < deg; j += 64) {
        int p = start + j;
        float e = dsc_d + ssc[src_sorted[p]] + rel_s[type_sorted[p]];
        e = (e > 0.f ? e : 0.2f * e) + lc_sorted[p];
        float nm = fmaxf(m_l, e);
        s_l = s_l * __expf(m_l - nm) + __expf(e - nm);
        m_l = nm;
    }
    float m = m_l;
    for (int off = 32; off; off >>= 1) m = fmaxf(m, __shfl_xor(m, off));
    float ssum = s_l * __expf(m_l - m);
    for (int off = 32; off; off >>= 1) ssum += __shfl_xor(ssum, off);

    // channel-parallel weighted gather (edges serial; all lanes recompute e)
    float2 acc = make_float2(0.f, 0.f);
    for (int k = 0; k < deg; ++k) {
        int p = start + k;
        int s = src_sorted[p];
        float e = dsc_d + ssc[s] + rel_s[type_sorted[p]];
        e = (e > 0.f ? e : 0.2f * e) + lc_sorted[p];
        float ex = __expf(e - m);
        float2 row = *(const float2*)(hm + (size_t)s * H_DIM + 2 * lane);
        acc.x += ex * row.x;
        acc.y += ex * row.y;
    }

    const float inv = (deg > 0) ? 1.f / ssum : 0.f;
    const int c = 2 * lane;
    float2 bs = *(const float2*)(bias_l + c);
    float2 hi = *(const float2*)(h_in + (size_t)d * H_DIM + c);
    float v0 = hi.x + fmaxf(acc.x * inv + bs.x, 0.f);
    float v1 = hi.y + fmaxf(acc.y * inv + bs.y, 0.f);

    float sum = v0 + v1;
    for (int off = 32; off; off >>= 1) sum += __shfl_xor(sum, off);
    float mu = sum * (1.f / H_DIM);
    float d0 = v0 - mu, d1 = v1 - mu;
    float vs = d0 * d0 + d1 * d1;
    for (int off = 32; off; off >>= 1) vs += __shfl_xor(vs, off);
    float invstd = rsqrtf(vs * (1.f / H_DIM) + LN_EPS);
    float2 gg = *(const float2*)(g + c);
    float2 bb = *(const float2*)(b + c);
    float2 o;
    o.x = d0 * invstd * gg.x + bb.x;
    o.y = d1 * invstd * gg.y + bb.y;
    *(float2*)(h_out + (size_t)d * H_DIM + c) = o;
}

extern "C" void kernel_launch(void* const* d_in, const int* in_sizes, int n_in,
                              void* d_out, int out_size, void* d_ws, size_t ws_size,
                              hipStream_t stream) {
    const float* x         = (const float*)d_in[0];
    const int*   edge_index= (const int*)d_in[1];
    const int*   edge_type = (const int*)d_in[2];
    const float* edge_attr = (const float*)d_in[3];
    const float* W_in      = (const float*)d_in[4];
    const float* b_in      = (const float*)d_in[5];
    const float* W_msg     = (const float*)d_in[6];
    const float* rel_emb   = (const float*)d_in[7];
    const float* W_rel     = (const float*)d_in[8];
    const float* att_vec   = (const float*)d_in[9];
    const float* bias      = (const float*)d_in[10];
    const float* ln_g      = (const float*)d_in[11];
    const float* ln_b      = (const float*)d_in[12];
    float* out = (float*)d_out;

    // workspace layout (~65 MB)
    char* w = (char*)d_ws;
    float* h_ws       = (float*)w; w += (size_t)N_NODES * H_DIM * 4;
    float* hm         = (float*)w; w += (size_t)N_NODES * H_DIM * 4;
    int*   rank       = (int*)w;   w += (size_t)NE * 4;
    int*   src_sorted = (int*)w;   w += (size_t)NE * 4;
    int*   type_sorted= (int*)w;   w += (size_t)NE * 4;
    float* lc_sorted  = (float*)w; w += (size_t)NE * 4;
    int*   counts     = (int*)w;   w += (size_t)N_NODES * 4;
    int*   offsets    = (int*)w;   w += (size_t)N_NODES * 4;
    float* dsc        = (float*)w; w += (size_t)N_NODES * 4;
    float* ssc        = (float*)w; w += (size_t)N_NODES * 4;
    float* rel_score  = (float*)w; w += (size_t)NL * NR * 4;
    int*   bsum       = (int*)w;   w += (size_t)NB_SCAN * 4;
    int*   bbase      = (int*)w;   w += (size_t)NB_SCAN * 4;

    const int* srcv = edge_index;
    const int* dstv = edge_index + NE;

    // ---- CSR build (once; dst is layer-invariant)
    k_zero_counts<<<(N_NODES + 255) / 256, 256, 0, stream>>>(counts);
    k_count<<<(NE + 255) / 256, 256, 0, stream>>>(dstv, counts, rank);
    k_scan1<<<NB_SCAN, 256, 0, stream>>>(counts, bsum);
    k_scan2<<<1, 64, 0, stream>>>(bsum, bbase);
    k_scan3<<<NB_SCAN, 256, 0, stream>>>(counts, bbase, offsets);
    k_perm<<<(NE + 255) / 256, 256, 0, stream>>>(srcv, dstv, edge_type, edge_attr,
                                                 offsets, rank, src_sorted,
                                                 type_sorted, lc_sorted);
    k_rel_score<<<1, 256, 0, stream>>>(rel_emb, W_rel, att_vec, rel_score);

    k_gemm<IN_DIM, true, true, false><<<dim3((N_NODES + 63) / 64, 2), 256, 0, stream>>>(
        x, W_in, b_in, h_ws, N_NODES, nullptr, nullptr, nullptr);

    for (int l = 0; l < NL; ++l) {
        k_zero_scores<<<(N_NODES + 255) / 256, 256, 0, stream>>>(dsc, ssc);
        k_gemm<H_DIM, false, false, true><<<dim3((N_NODES + 63) / 64, 2), 256, 0, stream>>>(
            h_ws, W_msg + (size_t)l * H_DIM * H_DIM, nullptr, hm, N_NODES,
            att_vec + (size_t)l * 3 * H_DIM, dsc, ssc);
        k_fused<<<(N_NODES + 3) / 4, 256, 0, stream>>>(
            offsets, counts, src_sorted, type_sorted, lc_sorted, dsc, ssc,
            rel_score + l * NR, hm, h_ws,
            bias + (size_t)l * H_DIM, ln_g + (size_t)l * H_DIM,
            ln_b + (size_t)l * H_DIM, (l == NL - 1) ? out : h_ws);
    }
}

// Round 7
// 364.171 us; speedup vs baseline: 3.1417x; 1.2673x over previous
//
#include <hip/hip_runtime.h>
#include <hip/hip_bf16.h>

#define N_NODES 50000
#define NE      800000
#define IN_DIM  256
#define H_DIM   128
#define NL      2
#define NR      8
#define RD_DIM  16
#define CONF_W  0.5f
#define LN_EPS  1e-5f

#define SCAN_CHUNK 1024
#define NB_SCAN    ((N_NODES + SCAN_CHUNK - 1) / SCAN_CHUNK)   // 49

typedef __attribute__((ext_vector_type(8))) short bf16x8;
typedef __attribute__((ext_vector_type(4))) float f32x4;

__device__ __forceinline__ unsigned short f2bf(float f) {
    unsigned u = __float_as_uint(f);
    u += 0x7fffu + ((u >> 16) & 1u);          // round-to-nearest-even
    return (unsigned short)(u >> 16);
}
__device__ __forceinline__ float bf2f(unsigned short v) {
    return __uint_as_float(((unsigned)v) << 16);
}

// ============ CSR build (dst is layer-invariant: build once per call) ============

__global__ void k_zero_counts(int* __restrict__ counts) {
    int i = blockIdx.x * 256 + threadIdx.x;
    if (i < N_NODES) counts[i] = 0;
}

__global__ void k_count(const int* __restrict__ dstv, int* __restrict__ counts,
                        int* __restrict__ rank) {
    int i = blockIdx.x * 256 + threadIdx.x;
    if (i >= NE) return;
    rank[i] = atomicAdd(counts + dstv[i], 1);
}

__global__ __launch_bounds__(256) void k_scan1(const int* __restrict__ counts,
                                               int* __restrict__ bsum) {
    __shared__ int lsum[256];
    const int t = threadIdx.x, b = blockIdx.x;
    const int base = b * SCAN_CHUNK + t * 4;
    int s = 0;
#pragma unroll
    for (int j = 0; j < 4; ++j) {
        int idx = base + j;
        if (idx < N_NODES) s += counts[idx];
    }
    lsum[t] = s;
    __syncthreads();
    for (int off = 128; off; off >>= 1) {
        if (t < off) lsum[t] += lsum[t + off];
        __syncthreads();
    }
    if (t == 0) bsum[b] = lsum[0];
}

__global__ void k_scan2(const int* __restrict__ bsum, int* __restrict__ bbase) {
    int lane = threadIdx.x & 63;
    int v = (lane < NB_SCAN) ? bsum[lane] : 0;
    int inc = v;
    for (int off = 1; off < 64; off <<= 1) {
        int tmp = __shfl_up(inc, off);
        if (lane >= off) inc += tmp;
    }
    if (lane < NB_SCAN) bbase[lane] = inc - v;   // exclusive
}

__global__ __launch_bounds__(256) void k_scan3(const int* __restrict__ counts,
                                               const int* __restrict__ bbase,
                                               int* __restrict__ offsets) {
    __shared__ int lsum[256];
    const int t = threadIdx.x, b = blockIdx.x;
    const int base = b * SCAN_CHUNK + t * 4;
    int c[4];
    int s = 0;
#pragma unroll
    for (int j = 0; j < 4; ++j) {
        int idx = base + j;
        c[j] = (idx < N_NODES) ? counts[idx] : 0;
        s += c[j];
    }
    lsum[t] = s;
    __syncthreads();
    for (int off = 1; off < 256; off <<= 1) {
        int v = (t >= off) ? lsum[t - off] : 0;
        __syncthreads();
        lsum[t] += v;
        __syncthreads();
    }
    int run = bbase[b] + lsum[t] - s;
#pragma unroll
    for (int j = 0; j < 4; ++j) {
        int idx = base + j;
        if (idx < N_NODES) { offsets[idx] = run; run += c[j]; }
    }
}

__global__ void k_perm(const int* __restrict__ srcv, const int* __restrict__ dstv,
                       const int* __restrict__ et, const float* __restrict__ ea,
                       const int* __restrict__ offsets, const int* __restrict__ rank,
                       int* __restrict__ src_sorted, int* __restrict__ type_sorted,
                       float* __restrict__ lc_sorted) {
    int i = blockIdx.x * 256 + threadIdx.x;
    if (i >= NE) return;
    int p = offsets[dstv[i]] + rank[i];
    src_sorted[p] = srcv[i];
    int t = et[i]; t = t < 0 ? 0 : (t > NR - 1 ? NR - 1 : t);
    type_sorted[p] = t;
    lc_sorted[p] = CONF_W * logf(fmaxf(ea[i], 1e-6f));
}

// ============ rel_score[l][r] = rel_emb[l][r] . (W_rel[l] @ a_r[l]) ============
__global__ void k_rel_score(const float* __restrict__ rel_emb,
                            const float* __restrict__ W_rel,
                            const float* __restrict__ att_vec,
                            float* __restrict__ rel_score) {
    __shared__ float wvec[NL][RD_DIM];
    int t = threadIdx.x;
    if (t < NL * RD_DIM) {
        int l = t / RD_DIM, d = t % RD_DIM;
        const float* wr = W_rel + ((size_t)l * RD_DIM + d) * H_DIM;
        const float* ar = att_vec + (size_t)l * 3 * H_DIM + 2 * H_DIM;
        float s = 0.f;
        for (int k = 0; k < H_DIM; ++k) s += wr[k] * ar[k];
        wvec[l][d] = s;
    }
    __syncthreads();
    if (t < NL * NR) {
        int l = t / NR, r = t % NR;
        const float* re = rel_emb + ((size_t)l * NR + r) * RD_DIM;
        float s = 0.f;
        for (int d = 0; d < RD_DIM; ++d) s += re[d] * wvec[l][d];
        rel_score[t] = s;
    }
}

// ============ transpose+convert weights to bf16 Wt[N][K] (once, tiny) ============
__global__ void k_cvt_weights(const float* __restrict__ W_in,
                              const float* __restrict__ W_msg,
                              unsigned short* __restrict__ Wt_in,
                              unsigned short* __restrict__ Wt_msg) {
    int i = blockIdx.x * 256 + threadIdx.x;
    if (i < H_DIM * IN_DIM) {                       // Wt_in[n*256+k] = W_in[k*128+n]
        int n = i >> 8, k = i & 255;
        Wt_in[i] = f2bf(W_in[(size_t)k * H_DIM + n]);
    } else if (i < H_DIM * IN_DIM + NL * H_DIM * H_DIM) {
        int r = i - H_DIM * IN_DIM;                 // Wt_msg[l][n*128+k] = W_msg[l][k*128+n]
        int l = r >> 14;
        int n = (r >> 7) & 127, k = r & 127;
        Wt_msg[r] = f2bf(W_msg[(size_t)l * H_DIM * H_DIM + (size_t)k * H_DIM + n]);
    }
}

__global__ void k_zero_scores(float* __restrict__ dsc, float* __restrict__ ssc) {
    int i = blockIdx.x * 256 + threadIdx.x;
    if (i < N_NODES) { dsc[i] = 0.f; ssc[i] = 0.f; }
}

// ============ bf16 MFMA GEMM: C[M x 128] = A[M x K] @ Wt^T ============
// A: fp32 (converted to bf16 on the fly during LDS staging)
// Bt: bf16, layout [N=128][K] (pre-transposed weight)
// BM=128, BN=128, BK=32; 4 waves, each computes 64x64 via 4x4 frags of 16x16x32.
// BIASRELU: Cf = relu(C + bias)  (fp32 out)
// SCORES:   Cb = bf16(C); dsc[m] += C_row.a_d, ssc[m] += C_row.a_s (fp32 acc)
template <int K, bool BIASRELU, bool SCORES>
__global__ __launch_bounds__(256) void k_gemm_mfma(
        const float* __restrict__ A, const unsigned short* __restrict__ Bt,
        const float* __restrict__ bias, float* __restrict__ Cf,
        unsigned short* __restrict__ Cb, int M,
        const float* __restrict__ att_vec_l,
        float* __restrict__ dsc, float* __restrict__ ssc) {
    __shared__ unsigned short As[128 * 40];   // stride 40 bf16 = 80 B (16B-aligned rows)
    __shared__ unsigned short Bs[128 * 40];
    const int t = threadIdx.x;
    const int wid = t >> 6, lane = t & 63;
    const int wr = wid >> 1, wc = wid & 1;    // wave tile (64M x 64N)
    const int lm = lane & 15, lg = lane >> 4; // frag row/col = lm, k-octet = lg
    const int m0 = blockIdx.x * 128;

    f32x4 acc[4][4] = {};

    for (int k0 = 0; k0 < K; k0 += 32) {
        // stage A: 128 rows x 32 cols fp32 -> bf16
#pragma unroll
        for (int i = 0; i < 4; ++i) {
            int flat = t + i * 256;
            int row = flat >> 3, c4 = flat & 7;
            int rm = m0 + row; rm = rm < M ? rm : M - 1;
            float4 fv = *(const float4*)(A + (size_t)rm * K + k0 + c4 * 4);
            uint2 pk;
            pk.x = (unsigned)f2bf(fv.x) | ((unsigned)f2bf(fv.y) << 16);
            pk.y = (unsigned)f2bf(fv.z) | ((unsigned)f2bf(fv.w) << 16);
            *(uint2*)(As + row * 40 + c4 * 4) = pk;
        }
        // stage Bt: 128 rows x 32 cols bf16 (linear copy)
#pragma unroll
        for (int i = 0; i < 2; ++i) {
            int flat = t + i * 256;
            int row = flat >> 2, ch = flat & 3;
            uint4 v = *(const uint4*)(Bt + (size_t)row * K + k0 + ch * 8);
            *(uint4*)(Bs + row * 40 + ch * 8) = v;
        }
        __syncthreads();
        bf16x8 a[4], b[4];
#pragma unroll
        for (int f = 0; f < 4; ++f) {
            a[f] = *(const bf16x8*)(As + (wr * 64 + f * 16 + lm) * 40 + lg * 8);
            b[f] = *(const bf16x8*)(Bs + (wc * 64 + f * 16 + lm) * 40 + lg * 8);
        }
#pragma unroll
        for (int fm = 0; fm < 4; ++fm)
#pragma unroll
            for (int fn = 0; fn < 4; ++fn)
                acc[fm][fn] = __builtin_amdgcn_mfma_f32_16x16x32_bf16(
                    a[fm], b[fn], acc[fm][fn], 0, 0, 0);
        __syncthreads();
    }

    float av[4], asv[4];
    if (SCORES) {
#pragma unroll
        for (int fn = 0; fn < 4; ++fn) {
            int n = wc * 64 + fn * 16 + lm;
            av[fn]  = att_vec_l[n];
            asv[fn] = att_vec_l[H_DIM + n];
        }
    }

#pragma unroll
    for (int fm = 0; fm < 4; ++fm) {
#pragma unroll
        for (int j = 0; j < 4; ++j) {
            int m = m0 + wr * 64 + fm * 16 + lg * 4 + j;   // C row (verified layout)
            bool valid = m < M;
            if (BIASRELU) {
#pragma unroll
                for (int fn = 0; fn < 4; ++fn) {
                    int n = wc * 64 + fn * 16 + lm;
                    float v = fmaxf(acc[fm][fn][j] + bias[n], 0.f);
                    if (valid) Cf[(size_t)m * H_DIM + n] = v;
                }
            }
            if (SCORES) {
                float pd = 0.f, ps = 0.f;
#pragma unroll
                for (int fn = 0; fn < 4; ++fn) {
                    int n = wc * 64 + fn * 16 + lm;
                    float v = acc[fm][fn][j];
                    if (valid) Cb[(size_t)m * H_DIM + n] = f2bf(v);
                    pd += v * av[fn];
                    ps += v * asv[fn];
                }
#pragma unroll
                for (int off = 8; off; off >>= 1) {   // reduce over the 16 n-lanes
                    pd += __shfl_xor(pd, off);
                    ps += __shfl_xor(ps, off);
                }
                if (lm == 0 && valid) {
                    atomicAdd(dsc + m, pd);
                    atomicAdd(ssc + m, ps);
                }
            }
        }
    }
}

// ============ fused per-node: online softmax + weighted gather (bf16 hm)
//              + bias + relu + residual + layernorm. One wave per node. ============
__global__ __launch_bounds__(256) void k_fused(
        const int* __restrict__ offsets, const int* __restrict__ counts,
        const int* __restrict__ src_sorted, const int* __restrict__ type_sorted,
        const float* __restrict__ lc_sorted,
        const float* __restrict__ dsc, const float* __restrict__ ssc,
        const float* __restrict__ rel_l,
        const unsigned short* __restrict__ hm, const float* __restrict__ h_in,
        const float* __restrict__ bias_l, const float* __restrict__ g,
        const float* __restrict__ b, float* __restrict__ h_out) {
    __shared__ float rel_s[NR];
    if (threadIdx.x < NR) rel_s[threadIdx.x] = rel_l[threadIdx.x];
    __syncthreads();

    const int wave = threadIdx.x >> 6, lane = threadIdx.x & 63;
    const int d = blockIdx.x * 4 + wave;
    if (d >= N_NODES) return;

    const int start = offsets[d];
    const int deg = counts[d];
    const float dsc_d = dsc[d];

    // online (m,s) pass, edge-parallel
    float m_l = -1e30f, s_l = 0.f;
    for (int j = lane; j < deg; j += 64) {
        int p = start + j;
        float e = dsc_d + ssc[src_sorted[p]] + rel_s[type_sorted[p]];
        e = (e > 0.f ? e : 0.2f * e) + lc_sorted[p];
        float nm = fmaxf(m_l, e);
        s_l = s_l * __expf(m_l - nm) + __expf(e - nm);
        m_l = nm;
    }
    float m = m_l;
    for (int off = 32; off; off >>= 1) m = fmaxf(m, __shfl_xor(m, off));
    float ssum = s_l * __expf(m_l - m);
    for (int off = 32; off; off >>= 1) ssum += __shfl_xor(ssum, off);

    // channel-parallel weighted gather (bf16 rows, 2 ch/lane)
    float2 acc = make_float2(0.f, 0.f);
    const int c = 2 * lane;
    for (int k = 0; k < deg; ++k) {
        int p = start + k;
        int s = src_sorted[p];
        float e = dsc_d + ssc[s] + rel_s[type_sorted[p]];
        e = (e > 0.f ? e : 0.2f * e) + lc_sorted[p];
        float ex = __expf(e - m);
        ushort2 rv = *(const ushort2*)(hm + (size_t)s * H_DIM + c);
        acc.x += ex * bf2f(rv.x);
        acc.y += ex * bf2f(rv.y);
    }

    const float inv = (deg > 0) ? 1.f / ssum : 0.f;
    float2 bs = *(const float2*)(bias_l + c);
    float2 hi = *(const float2*)(h_in + (size_t)d * H_DIM + c);
    float v0 = hi.x + fmaxf(acc.x * inv + bs.x, 0.f);
    float v1 = hi.y + fmaxf(acc.y * inv + bs.y, 0.f);

    float sum = v0 + v1;
    for (int off = 32; off; off >>= 1) sum += __shfl_xor(sum, off);
    float mu = sum * (1.f / H_DIM);
    float d0 = v0 - mu, d1 = v1 - mu;
    float vs = d0 * d0 + d1 * d1;
    for (int off = 32; off; off >>= 1) vs += __shfl_xor(vs, off);
    float invstd = rsqrtf(vs * (1.f / H_DIM) + LN_EPS);
    float2 gg = *(const float2*)(g + c);
    float2 bb = *(const float2*)(b + c);
    float2 o;
    o.x = d0 * invstd * gg.x + bb.x;
    o.y = d1 * invstd * gg.y + bb.y;
    *(float2*)(h_out + (size_t)d * H_DIM + c) = o;
}

extern "C" void kernel_launch(void* const* d_in, const int* in_sizes, int n_in,
                              void* d_out, int out_size, void* d_ws, size_t ws_size,
                              hipStream_t stream) {
    const float* x         = (const float*)d_in[0];
    const int*   edge_index= (const int*)d_in[1];
    const int*   edge_type = (const int*)d_in[2];
    const float* edge_attr = (const float*)d_in[3];
    const float* W_in      = (const float*)d_in[4];
    const float* b_in      = (const float*)d_in[5];
    const float* W_msg     = (const float*)d_in[6];
    const float* rel_emb   = (const float*)d_in[7];
    const float* W_rel     = (const float*)d_in[8];
    const float* att_vec   = (const float*)d_in[9];
    const float* bias      = (const float*)d_in[10];
    const float* ln_g      = (const float*)d_in[11];
    const float* ln_b      = (const float*)d_in[12];
    float* out = (float*)d_out;

    // workspace layout (~52 MB)
    char* w = (char*)d_ws;
    float* h_ws       = (float*)w; w += (size_t)N_NODES * H_DIM * 4;   // 25.6 MB
    unsigned short* hm_b = (unsigned short*)w; w += (size_t)N_NODES * H_DIM * 2; // 12.8 MB
    int*   rank       = (int*)w;   w += (size_t)NE * 4;
    int*   src_sorted = (int*)w;   w += (size_t)NE * 4;
    int*   type_sorted= (int*)w;   w += (size_t)NE * 4;
    float* lc_sorted  = (float*)w; w += (size_t)NE * 4;
    int*   counts     = (int*)w;   w += (size_t)N_NODES * 4;
    int*   offsets    = (int*)w;   w += (size_t)N_NODES * 4;
    float* dsc        = (float*)w; w += (size_t)N_NODES * 4;
    float* ssc        = (float*)w; w += (size_t)N_NODES * 4;
    unsigned short* Wt_in  = (unsigned short*)w; w += (size_t)H_DIM * IN_DIM * 2;
    unsigned short* Wt_msg = (unsigned short*)w; w += (size_t)NL * H_DIM * H_DIM * 2;
    float* rel_score  = (float*)w; w += 64 * 4;
    int*   bsum       = (int*)w;   w += 64 * 4;
    int*   bbase      = (int*)w;   w += 64 * 4;

    const int* srcv = edge_index;
    const int* dstv = edge_index + NE;

    // ---- CSR build (once; dst is layer-invariant)
    k_zero_counts<<<(N_NODES + 255) / 256, 256, 0, stream>>>(counts);
    k_count<<<(NE + 255) / 256, 256, 0, stream>>>(dstv, counts, rank);
    k_scan1<<<NB_SCAN, 256, 0, stream>>>(counts, bsum);
    k_scan2<<<1, 64, 0, stream>>>(bsum, bbase);
    k_scan3<<<NB_SCAN, 256, 0, stream>>>(counts, bbase, offsets);
    k_perm<<<(NE + 255) / 256, 256, 0, stream>>>(srcv, dstv, edge_type, edge_attr,
                                                 offsets, rank, src_sorted,
                                                 type_sorted, lc_sorted);
    k_rel_score<<<1, 256, 0, stream>>>(rel_emb, W_rel, att_vec, rel_score);
    k_cvt_weights<<<(H_DIM * IN_DIM + NL * H_DIM * H_DIM + 255) / 256, 256, 0, stream>>>(
        W_in, W_msg, Wt_in, Wt_msg);

    const int GB = (N_NODES + 127) / 128;   // 391
    k_gemm_mfma<IN_DIM, true, false><<<GB, 256, 0, stream>>>(
        x, Wt_in, b_in, h_ws, nullptr, N_NODES, nullptr, nullptr, nullptr);

    for (int l = 0; l < NL; ++l) {
        k_zero_scores<<<(N_NODES + 255) / 256, 256, 0, stream>>>(dsc, ssc);
        k_gemm_mfma<H_DIM, false, true><<<GB, 256, 0, stream>>>(
            h_ws, Wt_msg + (size_t)l * H_DIM * H_DIM, nullptr, nullptr, hm_b, N_NODES,
            att_vec + (size_t)l * 3 * H_DIM, dsc, ssc);
        k_fused<<<(N_NODES + 3) / 4, 256, 0, stream>>>(
            offsets, counts, src_sorted, type_sorted, lc_sorted, dsc, ssc,
            rel_score + l * NR, hm_b, h_ws,
            bias + (size_t)l * H_DIM, ln_g + (size_t)l * H_DIM,
            ln_b + (size_t)l * H_DIM, (l == NL - 1) ? out : h_ws);
    }
}

// Round 8
// 329.790 us; speedup vs baseline: 3.4692x; 1.1042x over previous
//
#include <hip/hip_runtime.h>
#include <hip/hip_bf16.h>

#define N_NODES 50000
#define NE      800000
#define IN_DIM  256
#define H_DIM   128
#define NL      2
#define NR      8
#define RD_DIM  16
#define CONF_W  0.5f
#define LN_EPS  1e-5f

#define SCAN_CHUNK 1024
#define NB_SCAN    ((N_NODES + SCAN_CHUNK - 1) / SCAN_CHUNK)   // 49
#define DCAP       128   // per-wave LDS-cached edges (max deg ~45 for Poisson-16)

typedef __attribute__((ext_vector_type(8))) short bf16x8;
typedef __attribute__((ext_vector_type(4))) float f32x4;

__device__ __forceinline__ unsigned short f2bf(float f) {
    unsigned u = __float_as_uint(f);
    u += 0x7fffu + ((u >> 16) & 1u);          // round-to-nearest-even
    return (unsigned short)(u >> 16);
}
__device__ __forceinline__ float bf2f(unsigned short v) {
    return __uint_as_float(((unsigned)v) << 16);
}

// ============ CSR build (dst is layer-invariant: build once per call) ============

__global__ void k_zero_counts(int* __restrict__ counts) {
    int i = blockIdx.x * 256 + threadIdx.x;
    if (i < N_NODES) counts[i] = 0;
}

__global__ void k_count(const int* __restrict__ dstv, int* __restrict__ counts,
                        int* __restrict__ rank) {
    int i = blockIdx.x * 256 + threadIdx.x;
    if (i >= NE) return;
    rank[i] = atomicAdd(counts + dstv[i], 1);
}

__global__ __launch_bounds__(256) void k_scan1(const int* __restrict__ counts,
                                               int* __restrict__ bsum) {
    __shared__ int lsum[256];
    const int t = threadIdx.x, b = blockIdx.x;
    const int base = b * SCAN_CHUNK + t * 4;
    int s = 0;
#pragma unroll
    for (int j = 0; j < 4; ++j) {
        int idx = base + j;
        if (idx < N_NODES) s += counts[idx];
    }
    lsum[t] = s;
    __syncthreads();
    for (int off = 128; off; off >>= 1) {
        if (t < off) lsum[t] += lsum[t + off];
        __syncthreads();
    }
    if (t == 0) bsum[b] = lsum[0];
}

__global__ void k_scan2(const int* __restrict__ bsum, int* __restrict__ bbase) {
    int lane = threadIdx.x & 63;
    int v = (lane < NB_SCAN) ? bsum[lane] : 0;
    int inc = v;
    for (int off = 1; off < 64; off <<= 1) {
        int tmp = __shfl_up(inc, off);
        if (lane >= off) inc += tmp;
    }
    if (lane < NB_SCAN) bbase[lane] = inc - v;   // exclusive
}

__global__ __launch_bounds__(256) void k_scan3(const int* __restrict__ counts,
                                               const int* __restrict__ bbase,
                                               int* __restrict__ offsets) {
    __shared__ int lsum[256];
    const int t = threadIdx.x, b = blockIdx.x;
    const int base = b * SCAN_CHUNK + t * 4;
    int c[4];
    int s = 0;
#pragma unroll
    for (int j = 0; j < 4; ++j) {
        int idx = base + j;
        c[j] = (idx < N_NODES) ? counts[idx] : 0;
        s += c[j];
    }
    lsum[t] = s;
    __syncthreads();
    for (int off = 1; off < 256; off <<= 1) {
        int v = (t >= off) ? lsum[t - off] : 0;
        __syncthreads();
        lsum[t] += v;
        __syncthreads();
    }
    int run = bbase[b] + lsum[t] - s;
#pragma unroll
    for (int j = 0; j < 4; ++j) {
        int idx = base + j;
        if (idx < N_NODES) { offsets[idx] = run; run += c[j]; }
    }
}

// scatter per-edge record {src|type<<16, bits(lc)} into dst-sorted order
__global__ void k_perm(const int* __restrict__ srcv, const int* __restrict__ dstv,
                       const int* __restrict__ et, const float* __restrict__ ea,
                       const int* __restrict__ offsets, const int* __restrict__ rank,
                       uint2* __restrict__ meta_sorted) {
    int i = blockIdx.x * 256 + threadIdx.x;
    if (i >= NE) return;
    int p = offsets[dstv[i]] + rank[i];
    int t = et[i]; t = t < 0 ? 0 : (t > NR - 1 ? NR - 1 : t);
    float lc = CONF_W * logf(fmaxf(ea[i], 1e-6f));
    meta_sorted[p] = make_uint2((unsigned)srcv[i] | ((unsigned)t << 16),
                                __float_as_uint(lc));
}

// ============ rel_score[l][r] = rel_emb[l][r] . (W_rel[l] @ a_r[l]) ============
__global__ void k_rel_score(const float* __restrict__ rel_emb,
                            const float* __restrict__ W_rel,
                            const float* __restrict__ att_vec,
                            float* __restrict__ rel_score) {
    __shared__ float wvec[NL][RD_DIM];
    int t = threadIdx.x;
    if (t < NL * RD_DIM) {
        int l = t / RD_DIM, d = t % RD_DIM;
        const float* wr = W_rel + ((size_t)l * RD_DIM + d) * H_DIM;
        const float* ar = att_vec + (size_t)l * 3 * H_DIM + 2 * H_DIM;
        float s = 0.f;
        for (int k = 0; k < H_DIM; ++k) s += wr[k] * ar[k];
        wvec[l][d] = s;
    }
    __syncthreads();
    if (t < NL * NR) {
        int l = t / NR, r = t % NR;
        const float* re = rel_emb + ((size_t)l * NR + r) * RD_DIM;
        float s = 0.f;
        for (int d = 0; d < RD_DIM; ++d) s += re[d] * wvec[l][d];
        rel_score[t] = s;
    }
}

// ============ transpose+convert weights to bf16 Wt[N][K] (once, tiny) ============
__global__ void k_cvt_weights(const float* __restrict__ W_in,
                              const float* __restrict__ W_msg,
                              unsigned short* __restrict__ Wt_in,
                              unsigned short* __restrict__ Wt_msg) {
    int i = blockIdx.x * 256 + threadIdx.x;
    if (i < H_DIM * IN_DIM) {                       // Wt_in[n*256+k] = W_in[k*128+n]
        int n = i >> 8, k = i & 255;
        Wt_in[i] = f2bf(W_in[(size_t)k * H_DIM + n]);
    } else if (i < H_DIM * IN_DIM + NL * H_DIM * H_DIM) {
        int r = i - H_DIM * IN_DIM;                 // Wt_msg[l][n*128+k] = W_msg[l][k*128+n]
        int l = r >> 14;
        int n = (r >> 7) & 127, k = r & 127;
        Wt_msg[r] = f2bf(W_msg[(size_t)l * H_DIM * H_DIM + (size_t)k * H_DIM + n]);
    }
}

// zero both layers' dsc/ssc in one dispatch
__global__ void k_zero_scores(float* __restrict__ dsc, float* __restrict__ ssc) {
    int i = blockIdx.x * 256 + threadIdx.x;
    if (i < NL * N_NODES) { dsc[i] = 0.f; ssc[i] = 0.f; }
}

// ============ bf16 MFMA GEMM: C[M x 128] = A[M x K] @ Wt^T ============
// ABF16: A is bf16 [M][K]; else fp32 (converted during staging)
// BM=128, BN=128, BK=32; 4 waves, each 64x64 via 4x4 frags of 16x16x32.
// BIASRELU: v = relu(C+bias) -> Cf fp32 (+ Cb bf16 if non-null)
// SCORES:   Cb = bf16(C); dsc[m] += C_row.a_d, ssc[m] += C_row.a_s
template <int K, bool ABF16, bool BIASRELU, bool SCORES>
__global__ __launch_bounds__(256) void k_gemm_mfma(
        const void* __restrict__ Av, const unsigned short* __restrict__ Bt,
        const float* __restrict__ bias, float* __restrict__ Cf,
        unsigned short* __restrict__ Cb, int M,
        const float* __restrict__ att_vec_l,
        float* __restrict__ dsc, float* __restrict__ ssc) {
    __shared__ unsigned short As[128 * 40];   // stride 40 bf16 = 80 B
    __shared__ unsigned short Bs[128 * 40];
    const int t = threadIdx.x;
    const int wid = t >> 6, lane = t & 63;
    const int wr = wid >> 1, wc = wid & 1;
    const int lm = lane & 15, lg = lane >> 4;
    const int m0 = blockIdx.x * 128;

    f32x4 acc[4][4] = {};

    for (int k0 = 0; k0 < K; k0 += 32) {
        if (ABF16) {
            const unsigned short* A = (const unsigned short*)Av;
#pragma unroll
            for (int i = 0; i < 2; ++i) {
                int flat = t + i * 256;
                int row = flat >> 2, ch = flat & 3;
                int rm = m0 + row; rm = rm < M ? rm : M - 1;
                uint4 v = *(const uint4*)(A + (size_t)rm * K + k0 + ch * 8);
                *(uint4*)(As + row * 40 + ch * 8) = v;
            }
        } else {
            const float* A = (const float*)Av;
#pragma unroll
            for (int i = 0; i < 4; ++i) {
                int flat = t + i * 256;
                int row = flat >> 3, c4 = flat & 7;
                int rm = m0 + row; rm = rm < M ? rm : M - 1;
                float4 fv = *(const float4*)(A + (size_t)rm * K + k0 + c4 * 4);
                uint2 pk;
                pk.x = (unsigned)f2bf(fv.x) | ((unsigned)f2bf(fv.y) << 16);
                pk.y = (unsigned)f2bf(fv.z) | ((unsigned)f2bf(fv.w) << 16);
                *(uint2*)(As + row * 40 + c4 * 4) = pk;
            }
        }
#pragma unroll
        for (int i = 0; i < 2; ++i) {
            int flat = t + i * 256;
            int row = flat >> 2, ch = flat & 3;
            uint4 v = *(const uint4*)(Bt + (size_t)row * K + k0 + ch * 8);
            *(uint4*)(Bs + row * 40 + ch * 8) = v;
        }
        __syncthreads();
        bf16x8 a[4], b[4];
#pragma unroll
        for (int f = 0; f < 4; ++f) {
            a[f] = *(const bf16x8*)(As + (wr * 64 + f * 16 + lm) * 40 + lg * 8);
            b[f] = *(const bf16x8*)(Bs + (wc * 64 + f * 16 + lm) * 40 + lg * 8);
        }
#pragma unroll
        for (int fm = 0; fm < 4; ++fm)
#pragma unroll
            for (int fn = 0; fn < 4; ++fn)
                acc[fm][fn] = __builtin_amdgcn_mfma_f32_16x16x32_bf16(
                    a[fm], b[fn], acc[fm][fn], 0, 0, 0);
        __syncthreads();
    }

    float av[4], asv[4];
    if (SCORES) {
#pragma unroll
        for (int fn = 0; fn < 4; ++fn) {
            int n = wc * 64 + fn * 16 + lm;
            av[fn]  = att_vec_l[n];
            asv[fn] = att_vec_l[H_DIM + n];
        }
    }

#pragma unroll
    for (int fm = 0; fm < 4; ++fm) {
#pragma unroll
        for (int j = 0; j < 4; ++j) {
            int m = m0 + wr * 64 + fm * 16 + lg * 4 + j;
            bool valid = m < M;
            if (BIASRELU) {
#pragma unroll
                for (int fn = 0; fn < 4; ++fn) {
                    int n = wc * 64 + fn * 16 + lm;
                    float v = fmaxf(acc[fm][fn][j] + bias[n], 0.f);
                    if (valid) {
                        Cf[(size_t)m * H_DIM + n] = v;
                        if (Cb) Cb[(size_t)m * H_DIM + n] = f2bf(v);
                    }
                }
            }
            if (SCORES) {
                float pd = 0.f, ps = 0.f;
#pragma unroll
                for (int fn = 0; fn < 4; ++fn) {
                    int n = wc * 64 + fn * 16 + lm;
                    float v = acc[fm][fn][j];
                    if (valid) Cb[(size_t)m * H_DIM + n] = f2bf(v);
                    pd += v * av[fn];
                    ps += v * asv[fn];
                }
#pragma unroll
                for (int off = 8; off; off >>= 1) {
                    pd += __shfl_xor(pd, off);
                    ps += __shfl_xor(ps, off);
                }
                if (lm == 0 && valid) {
                    atomicAdd(dsc + m, pd);
                    atomicAdd(ssc + m, ps);
                }
            }
        }
    }
}

// ============ fused per-node: softmax (LDS-cached weights) + gather + LN ============
__global__ __launch_bounds__(256) void k_fused(
        const int* __restrict__ offsets, const int* __restrict__ counts,
        const uint2* __restrict__ meta,
        const float* __restrict__ dsc, const float* __restrict__ ssc,
        const float* __restrict__ rel_l,
        const unsigned short* __restrict__ hm, const float* __restrict__ h_in,
        const float* __restrict__ bias_l, const float* __restrict__ g,
        const float* __restrict__ b, float* __restrict__ h_out,
        unsigned short* __restrict__ h_out_bf) {
    __shared__ float rel_s[NR];
    __shared__ float es[4][DCAP];
    __shared__ unsigned short srcs[4][DCAP];
    if (threadIdx.x < NR) rel_s[threadIdx.x] = rel_l[threadIdx.x];
    __syncthreads();

    const int wave = threadIdx.x >> 6, lane = threadIdx.x & 63;
    const int d = blockIdx.x * 4 + wave;   // grid exact: 12500*4 == 50000

    const int start = offsets[d];
    const int deg = counts[d];
    const float dsc_d = dsc[d];

    // pass 1: compute e once per edge, stash (e, src) in LDS, track max
    float m_l = -1e30f;
    for (int j = lane; j < deg; j += 64) {
        uint2 mv = meta[start + j];
        int s = mv.x & 0xffff;
        float e = dsc_d + ssc[s] + rel_s[(mv.x >> 16) & 7];
        e = (e > 0.f ? e : 0.2f * e) + __uint_as_float(mv.y);
        if (j < DCAP) { es[wave][j] = e; srcs[wave][j] = (unsigned short)s; }
        m_l = fmaxf(m_l, e);
    }
    float m = m_l;
    for (int off = 32; off; off >>= 1) m = fmaxf(m, __shfl_xor(m, off));

    // pass 1.5: e -> w = exp(e-m) in place; accumulate sum
    float s_l = 0.f;
    for (int j = lane; j < deg; j += 64) {
        float e;
        if (j < DCAP) e = es[wave][j];
        else {
            uint2 mv = meta[start + j];
            e = dsc_d + ssc[mv.x & 0xffff] + rel_s[(mv.x >> 16) & 7];
            e = (e > 0.f ? e : 0.2f * e) + __uint_as_float(mv.y);
        }
        float w = __expf(e - m);
        if (j < DCAP) es[wave][j] = w;
        s_l += w;
    }
    float ssum = s_l;
    for (int off = 32; off; off >>= 1) ssum += __shfl_xor(ssum, off);

    __syncthreads();   // make es/srcs visible across lanes

    // pass 2: serial lean gather — LDS broadcast w + bf16 row load + 2 FMA
    float2 acc = make_float2(0.f, 0.f);
    const int c = 2 * lane;
#pragma unroll 4
    for (int k = 0; k < deg; ++k) {
        float w;
        int s;
        if (k < DCAP) { w = es[wave][k]; s = srcs[wave][k]; }
        else {
            uint2 mv = meta[start + k];
            s = mv.x & 0xffff;
            float e = dsc_d + ssc[s] + rel_s[(mv.x >> 16) & 7];
            e = (e > 0.f ? e : 0.2f * e) + __uint_as_float(mv.y);
            w = __expf(e - m);
        }
        ushort2 rv = *(const ushort2*)(hm + (size_t)s * H_DIM + c);
        acc.x += w * bf2f(rv.x);
        acc.y += w * bf2f(rv.y);
    }

    const float inv = (deg > 0) ? 1.f / ssum : 0.f;
    float2 bs = *(const float2*)(bias_l + c);
    float2 hi = *(const float2*)(h_in + (size_t)d * H_DIM + c);
    float v0 = hi.x + fmaxf(acc.x * inv + bs.x, 0.f);
    float v1 = hi.y + fmaxf(acc.y * inv + bs.y, 0.f);

    float sum = v0 + v1;
    for (int off = 32; off; off >>= 1) sum += __shfl_xor(sum, off);
    float mu = sum * (1.f / H_DIM);
    float d0 = v0 - mu, d1 = v1 - mu;
    float vs = d0 * d0 + d1 * d1;
    for (int off = 32; off; off >>= 1) vs += __shfl_xor(vs, off);
    float invstd = rsqrtf(vs * (1.f / H_DIM) + LN_EPS);
    float2 gg = *(const float2*)(g + c);
    float2 bb = *(const float2*)(b + c);
    float2 o;
    o.x = d0 * invstd * gg.x + bb.x;
    o.y = d1 * invstd * gg.y + bb.y;
    *(float2*)(h_out + (size_t)d * H_DIM + c) = o;
    if (h_out_bf) {
        ushort2 ob = make_ushort2(f2bf(o.x), f2bf(o.y));
        *(ushort2*)(h_out_bf + (size_t)d * H_DIM + c) = ob;
    }
}

extern "C" void kernel_launch(void* const* d_in, const int* in_sizes, int n_in,
                              void* d_out, int out_size, void* d_ws, size_t ws_size,
                              hipStream_t stream) {
    const float* x         = (const float*)d_in[0];
    const int*   edge_index= (const int*)d_in[1];
    const int*   edge_type = (const int*)d_in[2];
    const float* edge_attr = (const float*)d_in[3];
    const float* W_in      = (const float*)d_in[4];
    const float* b_in      = (const float*)d_in[5];
    const float* W_msg     = (const float*)d_in[6];
    const float* rel_emb   = (const float*)d_in[7];
    const float* W_rel     = (const float*)d_in[8];
    const float* att_vec   = (const float*)d_in[9];
    const float* bias      = (const float*)d_in[10];
    const float* ln_g      = (const float*)d_in[11];
    const float* ln_b      = (const float*)d_in[12];
    float* out = (float*)d_out;

    // workspace layout (~62 MB)
    char* w = (char*)d_ws;
    float* h_ws       = (float*)w; w += (size_t)N_NODES * H_DIM * 4;   // 25.6 MB
    unsigned short* h_bf = (unsigned short*)w; w += (size_t)N_NODES * H_DIM * 2; // 12.8
    unsigned short* hm_b = (unsigned short*)w; w += (size_t)N_NODES * H_DIM * 2; // 12.8
    uint2* meta_sorted = (uint2*)w; w += (size_t)NE * 8;               //  6.4 MB
    int*   rank       = (int*)w;   w += (size_t)NE * 4;                //  3.2 MB
    int*   counts     = (int*)w;   w += (size_t)N_NODES * 4;
    int*   offsets    = (int*)w;   w += (size_t)N_NODES * 4;
    float* dsc        = (float*)w; w += (size_t)NL * N_NODES * 4;
    float* ssc        = (float*)w; w += (size_t)NL * N_NODES * 4;
    unsigned short* Wt_in  = (unsigned short*)w; w += (size_t)H_DIM * IN_DIM * 2;
    unsigned short* Wt_msg = (unsigned short*)w; w += (size_t)NL * H_DIM * H_DIM * 2;
    float* rel_score  = (float*)w; w += 64 * 4;
    int*   bsum       = (int*)w;   w += 64 * 4;
    int*   bbase      = (int*)w;   w += 64 * 4;

    const int* srcv = edge_index;
    const int* dstv = edge_index + NE;

    // ---- CSR build (once; dst is layer-invariant)
    k_zero_counts<<<(N_NODES + 255) / 256, 256, 0, stream>>>(counts);
    k_count<<<(NE + 255) / 256, 256, 0, stream>>>(dstv, counts, rank);
    k_scan1<<<NB_SCAN, 256, 0, stream>>>(counts, bsum);
    k_scan2<<<1, 64, 0, stream>>>(bsum, bbase);
    k_scan3<<<NB_SCAN, 256, 0, stream>>>(counts, bbase, offsets);
    k_perm<<<(NE + 255) / 256, 256, 0, stream>>>(srcv, dstv, edge_type, edge_attr,
                                                 offsets, rank, meta_sorted);
    k_rel_score<<<1, 256, 0, stream>>>(rel_emb, W_rel, att_vec, rel_score);
    k_cvt_weights<<<(H_DIM * IN_DIM + NL * H_DIM * H_DIM + 255) / 256, 256, 0, stream>>>(
        W_in, W_msg, Wt_in, Wt_msg);
    k_zero_scores<<<(NL * N_NODES + 255) / 256, 256, 0, stream>>>(dsc, ssc);

    const int GB = (N_NODES + 127) / 128;   // 391
    k_gemm_mfma<IN_DIM, false, true, false><<<GB, 256, 0, stream>>>(
        x, Wt_in, b_in, h_ws, h_bf, N_NODES, nullptr, nullptr, nullptr);

    for (int l = 0; l < NL; ++l) {
        k_gemm_mfma<H_DIM, true, false, true><<<GB, 256, 0, stream>>>(
            h_bf, Wt_msg + (size_t)l * H_DIM * H_DIM, nullptr, nullptr, hm_b, N_NODES,
            att_vec + (size_t)l * 3 * H_DIM, dsc + (size_t)l * N_NODES,
            ssc + (size_t)l * N_NODES);
        k_fused<<<N_NODES / 4, 256, 0, stream>>>(
            offsets, counts, meta_sorted,
            dsc + (size_t)l * N_NODES, ssc + (size_t)l * N_NODES,
            rel_score + l * NR, hm_b, h_ws,
            bias + (size_t)l * H_DIM, ln_g + (size_t)l * H_DIM,
            ln_b + (size_t)l * H_DIM,
            (l == NL - 1) ? out : h_ws,
            (l == NL - 1) ? nullptr : h_bf);
    }
}

// Round 9
// 309.685 us; speedup vs baseline: 3.6944x; 1.0649x over previous
//
#include <hip/hip_runtime.h>
#include <hip/hip_bf16.h>

#define N_NODES 50000
#define NE      800000
#define IN_DIM  256
#define H_DIM   128
#define NL      2
#define NR      8
#define RD_DIM  16
#define CONF_W  0.5f
#define LN_EPS  1e-5f

#define SCAN_CHUNK 1024
#define NB_SCAN    ((N_NODES + SCAN_CHUNK - 1) / SCAN_CHUNK)   // 49
#define DCAP       128   // per-wave LDS-cached edges (max deg ~45 for Poisson-16)

typedef __attribute__((ext_vector_type(8))) short bf16x8;
typedef __attribute__((ext_vector_type(4))) float f32x4;

__device__ __forceinline__ unsigned short f2bf(float f) {
    unsigned u = __float_as_uint(f);
    u += 0x7fffu + ((u >> 16) & 1u);          // round-to-nearest-even
    return (unsigned short)(u >> 16);
}
__device__ __forceinline__ float bf_lo(unsigned v) {   // low bf16 of packed u32
    return __uint_as_float(v << 16);
}
__device__ __forceinline__ float bf_hi(unsigned v) {   // high bf16 of packed u32
    return __uint_as_float(v & 0xffff0000u);
}

// ============ CSR build (dst is layer-invariant: build once per call) ============

__global__ void k_zero_counts(int* __restrict__ counts) {
    int i = blockIdx.x * 256 + threadIdx.x;
    if (i < N_NODES) counts[i] = 0;
}

__global__ void k_count(const int* __restrict__ dstv, int* __restrict__ counts,
                        int* __restrict__ rank) {
    int i = blockIdx.x * 256 + threadIdx.x;
    if (i >= NE) return;
    rank[i] = atomicAdd(counts + dstv[i], 1);
}

__global__ __launch_bounds__(256) void k_scan1(const int* __restrict__ counts,
                                               int* __restrict__ bsum) {
    __shared__ int lsum[256];
    const int t = threadIdx.x, b = blockIdx.x;
    const int base = b * SCAN_CHUNK + t * 4;
    int s = 0;
#pragma unroll
    for (int j = 0; j < 4; ++j) {
        int idx = base + j;
        if (idx < N_NODES) s += counts[idx];
    }
    lsum[t] = s;
    __syncthreads();
    for (int off = 128; off; off >>= 1) {
        if (t < off) lsum[t] += lsum[t + off];
        __syncthreads();
    }
    if (t == 0) bsum[b] = lsum[0];
}

__global__ void k_scan2(const int* __restrict__ bsum, int* __restrict__ bbase) {
    int lane = threadIdx.x & 63;
    int v = (lane < NB_SCAN) ? bsum[lane] : 0;
    int inc = v;
    for (int off = 1; off < 64; off <<= 1) {
        int tmp = __shfl_up(inc, off);
        if (lane >= off) inc += tmp;
    }
    if (lane < NB_SCAN) bbase[lane] = inc - v;   // exclusive
}

__global__ __launch_bounds__(256) void k_scan3(const int* __restrict__ counts,
                                               const int* __restrict__ bbase,
                                               int* __restrict__ offsets) {
    __shared__ int lsum[256];
    const int t = threadIdx.x, b = blockIdx.x;
    const int base = b * SCAN_CHUNK + t * 4;
    int c[4];
    int s = 0;
#pragma unroll
    for (int j = 0; j < 4; ++j) {
        int idx = base + j;
        c[j] = (idx < N_NODES) ? counts[idx] : 0;
        s += c[j];
    }
    lsum[t] = s;
    __syncthreads();
    for (int off = 1; off < 256; off <<= 1) {
        int v = (t >= off) ? lsum[t - off] : 0;
        __syncthreads();
        lsum[t] += v;
        __syncthreads();
    }
    int run = bbase[b] + lsum[t] - s;
#pragma unroll
    for (int j = 0; j < 4; ++j) {
        int idx = base + j;
        if (idx < N_NODES) { offsets[idx] = run; run += c[j]; }
    }
}

// scatter per-edge record {src|type<<16, bits(lc)} into dst-sorted order
__global__ void k_perm(const int* __restrict__ srcv, const int* __restrict__ dstv,
                       const int* __restrict__ et, const float* __restrict__ ea,
                       const int* __restrict__ offsets, const int* __restrict__ rank,
                       uint2* __restrict__ meta_sorted) {
    int i = blockIdx.x * 256 + threadIdx.x;
    if (i >= NE) return;
    int p = offsets[dstv[i]] + rank[i];
    int t = et[i]; t = t < 0 ? 0 : (t > NR - 1 ? NR - 1 : t);
    float lc = CONF_W * logf(fmaxf(ea[i], 1e-6f));
    meta_sorted[p] = make_uint2((unsigned)srcv[i] | ((unsigned)t << 16),
                                __float_as_uint(lc));
}

// ============ rel_score[l][r] = rel_emb[l][r] . (W_rel[l] @ a_r[l]) ============
__global__ void k_rel_score(const float* __restrict__ rel_emb,
                            const float* __restrict__ W_rel,
                            const float* __restrict__ att_vec,
                            float* __restrict__ rel_score) {
    __shared__ float wvec[NL][RD_DIM];
    int t = threadIdx.x;
    if (t < NL * RD_DIM) {
        int l = t / RD_DIM, d = t % RD_DIM;
        const float* wr = W_rel + ((size_t)l * RD_DIM + d) * H_DIM;
        const float* ar = att_vec + (size_t)l * 3 * H_DIM + 2 * H_DIM;
        float s = 0.f;
        for (int k = 0; k < H_DIM; ++k) s += wr[k] * ar[k];
        wvec[l][d] = s;
    }
    __syncthreads();
    if (t < NL * NR) {
        int l = t / NR, r = t % NR;
        const float* re = rel_emb + ((size_t)l * NR + r) * RD_DIM;
        float s = 0.f;
        for (int d = 0; d < RD_DIM; ++d) s += re[d] * wvec[l][d];
        rel_score[t] = s;
    }
}

// ============ setup: weight transpose+cvt AND zero dsc/ssc (one dispatch) ============
__global__ void k_setup(const float* __restrict__ W_in,
                        const float* __restrict__ W_msg,
                        unsigned short* __restrict__ Wt_in,
                        unsigned short* __restrict__ Wt_msg,
                        float* __restrict__ dsc, float* __restrict__ ssc) {
    int i = blockIdx.x * 256 + threadIdx.x;
    if (i < H_DIM * IN_DIM) {                       // Wt_in[n*256+k] = W_in[k*128+n]
        int n = i >> 8, k = i & 255;
        Wt_in[i] = f2bf(W_in[(size_t)k * H_DIM + n]);
    } else if (i < H_DIM * IN_DIM + NL * H_DIM * H_DIM) {
        int r = i - H_DIM * IN_DIM;                 // Wt_msg[l][n*128+k] = W_msg[l][k*128+n]
        int l = r >> 14;
        int n = (r >> 7) & 127, k = r & 127;
        Wt_msg[r] = f2bf(W_msg[(size_t)l * H_DIM * H_DIM + (size_t)k * H_DIM + n]);
    }
    if (i < NL * N_NODES) { dsc[i] = 0.f; ssc[i] = 0.f; }
}

// ============ bf16 MFMA GEMM: C[M x 128] = A[M x K] @ Wt^T, bf16 out ============
// ABF16: A is bf16 [M][K]; else fp32 (converted during staging)
// BIASRELU: Cb = bf16(relu(C + bias))
// SCORES:   Cb = bf16(C); dsc[m] += C_row.a_d, ssc[m] += C_row.a_s (fp32 acc)
template <int K, bool ABF16, bool BIASRELU, bool SCORES>
__global__ __launch_bounds__(256) void k_gemm_mfma(
        const void* __restrict__ Av, const unsigned short* __restrict__ Bt,
        const float* __restrict__ bias,
        unsigned short* __restrict__ Cb, int M,
        const float* __restrict__ att_vec_l,
        float* __restrict__ dsc, float* __restrict__ ssc) {
    __shared__ unsigned short As[128 * 40];   // stride 40 bf16 = 80 B
    __shared__ unsigned short Bs[128 * 40];
    const int t = threadIdx.x;
    const int wid = t >> 6, lane = t & 63;
    const int wr = wid >> 1, wc = wid & 1;
    const int lm = lane & 15, lg = lane >> 4;
    const int m0 = blockIdx.x * 128;

    f32x4 acc[4][4] = {};

    for (int k0 = 0; k0 < K; k0 += 32) {
        if (ABF16) {
            const unsigned short* A = (const unsigned short*)Av;
#pragma unroll
            for (int i = 0; i < 2; ++i) {
                int flat = t + i * 256;
                int row = flat >> 2, ch = flat & 3;
                int rm = m0 + row; rm = rm < M ? rm : M - 1;
                uint4 v = *(const uint4*)(A + (size_t)rm * K + k0 + ch * 8);
                *(uint4*)(As + row * 40 + ch * 8) = v;
            }
        } else {
            const float* A = (const float*)Av;
#pragma unroll
            for (int i = 0; i < 4; ++i) {
                int flat = t + i * 256;
                int row = flat >> 3, c4 = flat & 7;
                int rm = m0 + row; rm = rm < M ? rm : M - 1;
                float4 fv = *(const float4*)(A + (size_t)rm * K + k0 + c4 * 4);
                uint2 pk;
                pk.x = (unsigned)f2bf(fv.x) | ((unsigned)f2bf(fv.y) << 16);
                pk.y = (unsigned)f2bf(fv.z) | ((unsigned)f2bf(fv.w) << 16);
                *(uint2*)(As + row * 40 + c4 * 4) = pk;
            }
        }
#pragma unroll
        for (int i = 0; i < 2; ++i) {
            int flat = t + i * 256;
            int row = flat >> 2, ch = flat & 3;
            uint4 v = *(const uint4*)(Bt + (size_t)row * K + k0 + ch * 8);
            *(uint4*)(Bs + row * 40 + ch * 8) = v;
        }
        __syncthreads();
        bf16x8 a[4], b[4];
#pragma unroll
        for (int f = 0; f < 4; ++f) {
            a[f] = *(const bf16x8*)(As + (wr * 64 + f * 16 + lm) * 40 + lg * 8);
            b[f] = *(const bf16x8*)(Bs + (wc * 64 + f * 16 + lm) * 40 + lg * 8);
        }
#pragma unroll
        for (int fm = 0; fm < 4; ++fm)
#pragma unroll
            for (int fn = 0; fn < 4; ++fn)
                acc[fm][fn] = __builtin_amdgcn_mfma_f32_16x16x32_bf16(
                    a[fm], b[fn], acc[fm][fn], 0, 0, 0);
        __syncthreads();
    }

    float av[4], asv[4];
    if (SCORES) {
#pragma unroll
        for (int fn = 0; fn < 4; ++fn) {
            int n = wc * 64 + fn * 16 + lm;
            av[fn]  = att_vec_l[n];
            asv[fn] = att_vec_l[H_DIM + n];
        }
    }

#pragma unroll
    for (int fm = 0; fm < 4; ++fm) {
#pragma unroll
        for (int j = 0; j < 4; ++j) {
            int m = m0 + wr * 64 + fm * 16 + lg * 4 + j;
            bool valid = m < M;
            if (BIASRELU) {
#pragma unroll
                for (int fn = 0; fn < 4; ++fn) {
                    int n = wc * 64 + fn * 16 + lm;
                    float v = fmaxf(acc[fm][fn][j] + bias[n], 0.f);
                    if (valid) Cb[(size_t)m * H_DIM + n] = f2bf(v);
                }
            }
            if (SCORES) {
                float pd = 0.f, ps = 0.f;
#pragma unroll
                for (int fn = 0; fn < 4; ++fn) {
                    int n = wc * 64 + fn * 16 + lm;
                    float v = acc[fm][fn][j];
                    if (valid) Cb[(size_t)m * H_DIM + n] = f2bf(v);
                    pd += v * av[fn];
                    ps += v * asv[fn];
                }
#pragma unroll
                for (int off = 8; off; off >>= 1) {
                    pd += __shfl_xor(pd, off);
                    ps += __shfl_xor(ps, off);
                }
                if (lm == 0 && valid) {
                    atomicAdd(dsc + m, pd);
                    atomicAdd(ssc + m, ps);
                }
            }
        }
    }
}

// ============ fused per-node: softmax + 4-edge-parallel gather + LN ============
// One wave per node. Gather: 16-lane group g handles edge k0+g; lane sub=lane&15
// loads 8 bf16 channels (uint4). Group partials merged via shfl_xor(16|32).
__global__ __launch_bounds__(256) void k_fused(
        const int* __restrict__ offsets, const int* __restrict__ counts,
        const uint2* __restrict__ meta,
        const float* __restrict__ dsc, const float* __restrict__ ssc,
        const float* __restrict__ rel_l,
        const unsigned short* __restrict__ hm,
        const unsigned short* __restrict__ h_in_bf,
        const float* __restrict__ bias_l, const float* __restrict__ g,
        const float* __restrict__ b,
        float* __restrict__ h_out_f32, unsigned short* __restrict__ h_out_bf) {
    __shared__ float rel_s[NR];
    __shared__ float es[4][DCAP];
    __shared__ unsigned short srcs[4][DCAP];
    if (threadIdx.x < NR) rel_s[threadIdx.x] = rel_l[threadIdx.x];
    __syncthreads();

    const int wave = threadIdx.x >> 6, lane = threadIdx.x & 63;
    const int sub = lane & 15, grp = lane >> 4;
    const int d = blockIdx.x * 4 + wave;   // grid exact: 12500*4 == 50000

    const int start = offsets[d];
    const int deg = counts[d];
    const float dsc_d = dsc[d];

    // pass 1: logits once per edge -> LDS; wave max
    float m_l = -1e30f;
    for (int j = lane; j < deg; j += 64) {
        uint2 mv = meta[start + j];
        int s = mv.x & 0xffff;
        float e = dsc_d + ssc[s] + rel_s[(mv.x >> 16) & 7];
        e = (e > 0.f ? e : 0.2f * e) + __uint_as_float(mv.y);
        if (j < DCAP) { es[wave][j] = e; srcs[wave][j] = (unsigned short)s; }
        m_l = fmaxf(m_l, e);
    }
    float m = m_l;
    for (int off = 32; off; off >>= 1) m = fmaxf(m, __shfl_xor(m, off));

    __syncthreads();   // es/srcs visible to all lanes

    // pass 2: 4-edge-parallel gather; ssum accumulated alongside
    float a0 = 0.f, a1 = 0.f, a2 = 0.f, a3 = 0.f,
          a4 = 0.f, a5 = 0.f, a6 = 0.f, a7 = 0.f;
    float s_part = 0.f;
#pragma unroll 2
    for (int k0 = 0; k0 < deg; k0 += 4) {
        int k = k0 + grp;
        if (k < deg) {
            float e; int s;
            if (k < DCAP) { e = es[wave][k]; s = srcs[wave][k]; }
            else {
                uint2 mv = meta[start + k];
                s = mv.x & 0xffff;
                e = dsc_d + ssc[s] + rel_s[(mv.x >> 16) & 7];
                e = (e > 0.f ? e : 0.2f * e) + __uint_as_float(mv.y);
            }
            float w = __expf(e - m);
            s_part += w;
            uint4 rv = *(const uint4*)(hm + (size_t)s * H_DIM + sub * 8);
            a0 += w * bf_lo(rv.x); a1 += w * bf_hi(rv.x);
            a2 += w * bf_lo(rv.y); a3 += w * bf_hi(rv.y);
            a4 += w * bf_lo(rv.z); a5 += w * bf_hi(rv.z);
            a6 += w * bf_lo(rv.w); a7 += w * bf_hi(rv.w);
        }
    }
    // merge the 4 groups (16-lane-group partials; sub-lanes within a group
    // hold identical s_part, so the 2-step xor yields the true total)
    a0 += __shfl_xor(a0, 16); a1 += __shfl_xor(a1, 16);
    a2 += __shfl_xor(a2, 16); a3 += __shfl_xor(a3, 16);
    a4 += __shfl_xor(a4, 16); a5 += __shfl_xor(a5, 16);
    a6 += __shfl_xor(a6, 16); a7 += __shfl_xor(a7, 16);
    s_part += __shfl_xor(s_part, 16);
    a0 += __shfl_xor(a0, 32); a1 += __shfl_xor(a1, 32);
    a2 += __shfl_xor(a2, 32); a3 += __shfl_xor(a3, 32);
    a4 += __shfl_xor(a4, 32); a5 += __shfl_xor(a5, 32);
    a6 += __shfl_xor(a6, 32); a7 += __shfl_xor(a7, 32);
    s_part += __shfl_xor(s_part, 32);

    const float inv = (deg > 0) ? 1.f / s_part : 0.f;

    // residual (bf16) + bias + relu on channels sub*8 .. sub*8+7
    uint4 hv = *(const uint4*)(h_in_bf + (size_t)d * H_DIM + sub * 8);
    float4 b0 = *(const float4*)(bias_l + sub * 8);
    float4 b1 = *(const float4*)(bias_l + sub * 8 + 4);
    float v0 = bf_lo(hv.x) + fmaxf(a0 * inv + b0.x, 0.f);
    float v1 = bf_hi(hv.x) + fmaxf(a1 * inv + b0.y, 0.f);
    float v2 = bf_lo(hv.y) + fmaxf(a2 * inv + b0.z, 0.f);
    float v3 = bf_hi(hv.y) + fmaxf(a3 * inv + b0.w, 0.f);
    float v4 = bf_lo(hv.z) + fmaxf(a4 * inv + b1.x, 0.f);
    float v5 = bf_hi(hv.z) + fmaxf(a5 * inv + b1.y, 0.f);
    float v6 = bf_lo(hv.w) + fmaxf(a6 * inv + b1.z, 0.f);
    float v7 = bf_hi(hv.w) + fmaxf(a7 * inv + b1.w, 0.f);

    // layernorm: every lane holds 8 channels; groups are duplicates, so the
    // 64-lane sum = 4 x (sum over 128 channels) -> divide by 512
    float sum = v0 + v1 + v2 + v3 + v4 + v5 + v6 + v7;
    for (int off = 32; off; off >>= 1) sum += __shfl_xor(sum, off);
    float mu = sum * (1.f / (H_DIM * 4));
    float d0 = v0 - mu, d1 = v1 - mu, d2 = v2 - mu, d3 = v3 - mu;
    float d4 = v4 - mu, d5 = v5 - mu, d6 = v6 - mu, d7 = v7 - mu;
    float vs = d0 * d0 + d1 * d1 + d2 * d2 + d3 * d3 +
               d4 * d4 + d5 * d5 + d6 * d6 + d7 * d7;
    for (int off = 32; off; off >>= 1) vs += __shfl_xor(vs, off);
    float invstd = rsqrtf(vs * (1.f / (H_DIM * 4)) + LN_EPS);

    float4 g0 = *(const float4*)(g + sub * 8);
    float4 g1 = *(const float4*)(g + sub * 8 + 4);
    float4 bb0 = *(const float4*)(b + sub * 8);
    float4 bb1 = *(const float4*)(b + sub * 8 + 4);
    float o0 = d0 * invstd * g0.x + bb0.x;
    float o1 = d1 * invstd * g0.y + bb0.y;
    float o2 = d2 * invstd * g0.z + bb0.z;
    float o3 = d3 * invstd * g0.w + bb0.w;
    float o4 = d4 * invstd * g1.x + bb1.x;
    float o5 = d5 * invstd * g1.y + bb1.y;
    float o6 = d6 * invstd * g1.z + bb1.z;
    float o7 = d7 * invstd * g1.w + bb1.w;

    if (grp == 0) {   // groups hold identical results; one group stores the row
        if (h_out_f32) {
            float* p = h_out_f32 + (size_t)d * H_DIM + sub * 8;
            *(float4*)p = make_float4(o0, o1, o2, o3);
            *(float4*)(p + 4) = make_float4(o4, o5, o6, o7);
        }
        if (h_out_bf) {
            uint4 pk;
            pk.x = (unsigned)f2bf(o0) | ((unsigned)f2bf(o1) << 16);
            pk.y = (unsigned)f2bf(o2) | ((unsigned)f2bf(o3) << 16);
            pk.z = (unsigned)f2bf(o4) | ((unsigned)f2bf(o5) << 16);
            pk.w = (unsigned)f2bf(o6) | ((unsigned)f2bf(o7) << 16);
            *(uint4*)(h_out_bf + (size_t)d * H_DIM + sub * 8) = pk;
        }
    }
}

extern "C" void kernel_launch(void* const* d_in, const int* in_sizes, int n_in,
                              void* d_out, int out_size, void* d_ws, size_t ws_size,
                              hipStream_t stream) {
    const float* x         = (const float*)d_in[0];
    const int*   edge_index= (const int*)d_in[1];
    const int*   edge_type = (const int*)d_in[2];
    const float* edge_attr = (const float*)d_in[3];
    const float* W_in      = (const float*)d_in[4];
    const float* b_in      = (const float*)d_in[5];
    const float* W_msg     = (const float*)d_in[6];
    const float* rel_emb   = (const float*)d_in[7];
    const float* W_rel     = (const float*)d_in[8];
    const float* att_vec   = (const float*)d_in[9];
    const float* bias      = (const float*)d_in[10];
    const float* ln_g      = (const float*)d_in[11];
    const float* ln_b      = (const float*)d_in[12];
    float* out = (float*)d_out;

    // workspace layout (~37 MB)
    char* w = (char*)d_ws;
    unsigned short* h_bf = (unsigned short*)w; w += (size_t)N_NODES * H_DIM * 2; // 12.8
    unsigned short* hm_b = (unsigned short*)w; w += (size_t)N_NODES * H_DIM * 2; // 12.8
    uint2* meta_sorted = (uint2*)w; w += (size_t)NE * 8;               //  6.4 MB
    int*   rank       = (int*)w;   w += (size_t)NE * 4;                //  3.2 MB
    int*   counts     = (int*)w;   w += (size_t)N_NODES * 4;
    int*   offsets    = (int*)w;   w += (size_t)N_NODES * 4;
    float* dsc        = (float*)w; w += (size_t)NL * N_NODES * 4;
    float* ssc        = (float*)w; w += (size_t)NL * N_NODES * 4;
    unsigned short* Wt_in  = (unsigned short*)w; w += (size_t)H_DIM * IN_DIM * 2;
    unsigned short* Wt_msg = (unsigned short*)w; w += (size_t)NL * H_DIM * H_DIM * 2;
    float* rel_score  = (float*)w; w += 64 * 4;
    int*   bsum       = (int*)w;   w += 64 * 4;
    int*   bbase      = (int*)w;   w += 64 * 4;

    const int* srcv = edge_index;
    const int* dstv = edge_index + NE;

    // ---- CSR build (once; dst is layer-invariant)
    k_zero_counts<<<(N_NODES + 255) / 256, 256, 0, stream>>>(counts);
    k_count<<<(NE + 255) / 256, 256, 0, stream>>>(dstv, counts, rank);
    k_scan1<<<NB_SCAN, 256, 0, stream>>>(counts, bsum);
    k_scan2<<<1, 64, 0, stream>>>(bsum, bbase);
    k_scan3<<<NB_SCAN, 256, 0, stream>>>(counts, bbase, offsets);
    k_perm<<<(NE + 255) / 256, 256, 0, stream>>>(srcv, dstv, edge_type, edge_attr,
                                                 offsets, rank, meta_sorted);
    k_rel_score<<<1, 256, 0, stream>>>(rel_emb, W_rel, att_vec, rel_score);
    k_setup<<<(NL * N_NODES + 255) / 256, 256, 0, stream>>>(
        W_in, W_msg, Wt_in, Wt_msg, dsc, ssc);

    const int GB = (N_NODES + 127) / 128;   // 391
    k_gemm_mfma<IN_DIM, false, true, false><<<GB, 256, 0, stream>>>(
        x, Wt_in, b_in, h_bf, N_NODES, nullptr, nullptr, nullptr);

    for (int l = 0; l < NL; ++l) {
        k_gemm_mfma<H_DIM, true, false, true><<<GB, 256, 0, stream>>>(
            h_bf, Wt_msg + (size_t)l * H_DIM * H_DIM, nullptr, hm_b, N_NODES,
            att_vec + (size_t)l * 3 * H_DIM, dsc + (size_t)l * N_NODES,
            ssc + (size_t)l * N_NODES);
        k_fused<<<N_NODES / 4, 256, 0, stream>>>(
            offsets, counts, meta_sorted,
            dsc + (size_t)l * N_NODES, ssc + (size_t)l * N_NODES,
            rel_score + l * NR, hm_b, h_bf,
            bias + (size_t)l * H_DIM, ln_g + (size_t)l * H_DIM,
            ln_b + (size_t)l * H_DIM,
            (l == NL - 1) ? out : nullptr,
            (l == NL - 1) ? nullptr : h_bf);
    }
}

// Round 11
// 309.112 us; speedup vs baseline: 3.7013x; 1.0019x over previous
//
#include <hip/hip_runtime.h>
#include <hip/hip_bf16.h>

#define N_NODES 50000
#define NE      800000
#define IN_DIM  256
#define H_DIM   128
#define NL      2
#define NR      8
#define RD_DIM  16
#define CONF_W  0.5f
#define LN_EPS  1e-5f

#define SCAN_CHUNK 1024
#define NB_SCAN    ((N_NODES + SCAN_CHUNK - 1) / SCAN_CHUNK)   // 49
#define DCAP       192   // per-wave LDS-cached edges (max deg ~45 for Poisson-16)

typedef __attribute__((ext_vector_type(8))) short bf16x8;
typedef __attribute__((ext_vector_type(4))) float f32x4;

__device__ __forceinline__ unsigned short f2bf(float f) {
    unsigned u = __float_as_uint(f);
    u += 0x7fffu + ((u >> 16) & 1u);          // round-to-nearest-even
    return (unsigned short)(u >> 16);
}
__device__ __forceinline__ float bf_lo(unsigned v) {   // low bf16 of packed u32
    return __uint_as_float(v << 16);
}
__device__ __forceinline__ float bf_hi(unsigned v) {   // high bf16 of packed u32
    return __uint_as_float(v & 0xffff0000u);
}

// ============ CSR build (dst is layer-invariant: build once per call) ============

__global__ void k_count(const int* __restrict__ dstv, int* __restrict__ counts,
                        int* __restrict__ rank) {
    int i = blockIdx.x * 256 + threadIdx.x;
    if (i >= NE) return;
    rank[i] = atomicAdd(counts + dstv[i], 1);
}

__global__ __launch_bounds__(256) void k_scan1(const int* __restrict__ counts,
                                               int* __restrict__ bsum) {
    __shared__ int lsum[256];
    const int t = threadIdx.x, b = blockIdx.x;
    const int base = b * SCAN_CHUNK + t * 4;
    int s = 0;
#pragma unroll
    for (int j = 0; j < 4; ++j) {
        int idx = base + j;
        if (idx < N_NODES) s += counts[idx];
    }
    lsum[t] = s;
    __syncthreads();
    for (int off = 128; off; off >>= 1) {
        if (t < off) lsum[t] += lsum[t + off];
        __syncthreads();
    }
    if (t == 0) bsum[b] = lsum[0];
}

__global__ void k_scan2(const int* __restrict__ bsum, int* __restrict__ bbase) {
    int lane = threadIdx.x & 63;
    int v = (lane < NB_SCAN) ? bsum[lane] : 0;
    int inc = v;
    for (int off = 1; off < 64; off <<= 1) {
        int tmp = __shfl_up(inc, off);
        if (lane >= off) inc += tmp;
    }
    if (lane < NB_SCAN) bbase[lane] = inc - v;   // exclusive
}

__global__ __launch_bounds__(256) void k_scan3(const int* __restrict__ counts,
                                               const int* __restrict__ bbase,
                                               int* __restrict__ offsets) {
    __shared__ int lsum[256];
    const int t = threadIdx.x, b = blockIdx.x;
    const int base = b * SCAN_CHUNK + t * 4;
    int c[4];
    int s = 0;
#pragma unroll
    for (int j = 0; j < 4; ++j) {
        int idx = base + j;
        c[j] = (idx < N_NODES) ? counts[idx] : 0;
        s += c[j];
    }
    lsum[t] = s;
    __syncthreads();
    for (int off = 1; off < 256; off <<= 1) {
        int v = (t >= off) ? lsum[t - off] : 0;
        __syncthreads();
        lsum[t] += v;
        __syncthreads();
    }
    int run = bbase[b] + lsum[t] - s;
#pragma unroll
    for (int j = 0; j < 4; ++j) {
        int idx = base + j;
        if (idx < N_NODES) { offsets[idx] = run; run += c[j]; }
    }
}

// scatter per-edge record {src|type<<16, bits(lc)} into dst-sorted order
__global__ void k_perm(const int* __restrict__ srcv, const int* __restrict__ dstv,
                       const int* __restrict__ et, const float* __restrict__ ea,
                       const int* __restrict__ offsets, const int* __restrict__ rank,
                       uint2* __restrict__ meta_sorted) {
    int i = blockIdx.x * 256 + threadIdx.x;
    if (i >= NE) return;
    int p = offsets[dstv[i]] + rank[i];
    int t = et[i]; t = t < 0 ? 0 : (t > NR - 1 ? NR - 1 : t);
    float lc = CONF_W * logf(fmaxf(ea[i], 1e-6f));
    meta_sorted[p] = make_uint2((unsigned)srcv[i] | ((unsigned)t << 16),
                                __float_as_uint(lc));
}

// ============ setup: weight cvt+transpose, zero counts/dsc/ssc, rel_score ============
__global__ void k_setup(const float* __restrict__ W_in,
                        const float* __restrict__ W_msg,
                        const float* __restrict__ rel_emb,
                        const float* __restrict__ W_rel,
                        const float* __restrict__ att_vec,
                        unsigned short* __restrict__ Wt_in,
                        unsigned short* __restrict__ Wt_msg,
                        float* __restrict__ dsc, float* __restrict__ ssc,
                        int* __restrict__ counts,
                        float* __restrict__ rel_score) {
    int i = blockIdx.x * 256 + threadIdx.x;
    if (i < H_DIM * IN_DIM) {                       // Wt_in[n*256+k] = W_in[k*128+n]
        int n = i >> 8, k = i & 255;
        Wt_in[i] = f2bf(W_in[(size_t)k * H_DIM + n]);
    } else if (i < H_DIM * IN_DIM + NL * H_DIM * H_DIM) {
        int r = i - H_DIM * IN_DIM;                 // Wt_msg[l][n*128+k] = W_msg[l][k*128+n]
        int l = r >> 14;
        int n = (r >> 7) & 127, k = r & 127;
        Wt_msg[r] = f2bf(W_msg[(size_t)l * H_DIM * H_DIM + (size_t)k * H_DIM + n]);
    }
    if (i < NL * N_NODES) { dsc[i] = 0.f; ssc[i] = 0.f; }
    if (i < N_NODES) counts[i] = 0;

    if (blockIdx.x == 0) {
        __shared__ float wvec[NL][RD_DIM];
        int t = threadIdx.x;
        if (t < NL * RD_DIM) {
            int l = t / RD_DIM, d = t % RD_DIM;
            const float* wr = W_rel + ((size_t)l * RD_DIM + d) * H_DIM;
            const float* ar = att_vec + (size_t)l * 3 * H_DIM + 2 * H_DIM;
            float s = 0.f;
            for (int k = 0; k < H_DIM; ++k) s += wr[k] * ar[k];
            wvec[l][d] = s;
        }
        __syncthreads();
        if (t < NL * NR) {
            int l = t / NR, r = t % NR;
            const float* re = rel_emb + ((size_t)l * NR + r) * RD_DIM;
            float s = 0.f;
            for (int d = 0; d < RD_DIM; ++d) s += re[d] * wvec[l][d];
            rel_score[t] = s;
        }
    }
}

// ============ bf16 MFMA GEMM: C[M x 128] = A[M x K] @ Wt^T, bf16 out ============
template <int K, bool ABF16, bool BIASRELU, bool SCORES>
__global__ __launch_bounds__(256) void k_gemm_mfma(
        const void* __restrict__ Av, const unsigned short* __restrict__ Bt,
        const float* __restrict__ bias,
        unsigned short* __restrict__ Cb, int M,
        const float* __restrict__ att_vec_l,
        float* __restrict__ dsc, float* __restrict__ ssc) {
    __shared__ unsigned short As[128 * 40];   // stride 40 bf16 = 80 B
    __shared__ unsigned short Bs[128 * 40];
    const int t = threadIdx.x;
    const int wid = t >> 6, lane = t & 63;
    const int wr = wid >> 1, wc = wid & 1;
    const int lm = lane & 15, lg = lane >> 4;
    const int m0 = blockIdx.x * 128;

    f32x4 acc[4][4] = {};

    for (int k0 = 0; k0 < K; k0 += 32) {
        if (ABF16) {
            const unsigned short* A = (const unsigned short*)Av;
#pragma unroll
            for (int i = 0; i < 2; ++i) {
                int flat = t + i * 256;
                int row = flat >> 2, ch = flat & 3;
                int rm = m0 + row; rm = rm < M ? rm : M - 1;
                uint4 v = *(const uint4*)(A + (size_t)rm * K + k0 + ch * 8);
                *(uint4*)(As + row * 40 + ch * 8) = v;
            }
        } else {
            const float* A = (const float*)Av;
#pragma unroll
            for (int i = 0; i < 4; ++i) {
                int flat = t + i * 256;
                int row = flat >> 3, c4 = flat & 7;
                int rm = m0 + row; rm = rm < M ? rm : M - 1;
                float4 fv = *(const float4*)(A + (size_t)rm * K + k0 + c4 * 4);
                uint2 pk;
                pk.x = (unsigned)f2bf(fv.x) | ((unsigned)f2bf(fv.y) << 16);
                pk.y = (unsigned)f2bf(fv.z) | ((unsigned)f2bf(fv.w) << 16);
                *(uint2*)(As + row * 40 + c4 * 4) = pk;
            }
        }
#pragma unroll
        for (int i = 0; i < 2; ++i) {
            int flat = t + i * 256;
            int row = flat >> 2, ch = flat & 3;
            uint4 v = *(const uint4*)(Bt + (size_t)row * K + k0 + ch * 8);
            *(uint4*)(Bs + row * 40 + ch * 8) = v;
        }
        __syncthreads();
        bf16x8 a[4], b[4];
#pragma unroll
        for (int f = 0; f < 4; ++f) {
            a[f] = *(const bf16x8*)(As + (wr * 64 + f * 16 + lm) * 40 + lg * 8);
            b[f] = *(const bf16x8*)(Bs + (wc * 64 + f * 16 + lm) * 40 + lg * 8);
        }
#pragma unroll
        for (int fm = 0; fm < 4; ++fm)
#pragma unroll
            for (int fn = 0; fn < 4; ++fn)
                acc[fm][fn] = __builtin_amdgcn_mfma_f32_16x16x32_bf16(
                    a[fm], b[fn], acc[fm][fn], 0, 0, 0);
        __syncthreads();
    }

    float av[4], asv[4];
    if (SCORES) {
#pragma unroll
        for (int fn = 0; fn < 4; ++fn) {
            int n = wc * 64 + fn * 16 + lm;
            av[fn]  = att_vec_l[n];
            asv[fn] = att_vec_l[H_DIM + n];
        }
    }

#pragma unroll
    for (int fm = 0; fm < 4; ++fm) {
#pragma unroll
        for (int j = 0; j < 4; ++j) {
            int m = m0 + wr * 64 + fm * 16 + lg * 4 + j;
            bool valid = m < M;
            if (BIASRELU) {
#pragma unroll
                for (int fn = 0; fn < 4; ++fn) {
                    int n = wc * 64 + fn * 16 + lm;
                    float v = fmaxf(acc[fm][fn][j] + bias[n], 0.f);
                    if (valid) Cb[(size_t)m * H_DIM + n] = f2bf(v);
                }
            }
            if (SCORES) {
                float pd = 0.f, ps = 0.f;
#pragma unroll
                for (int fn = 0; fn < 4; ++fn) {
                    int n = wc * 64 + fn * 16 + lm;
                    float v = acc[fm][fn][j];
                    if (valid) Cb[(size_t)m * H_DIM + n] = f2bf(v);
                    pd += v * av[fn];
                    ps += v * asv[fn];
                }
#pragma unroll
                for (int off = 8; off; off >>= 1) {
                    pd += __shfl_xor(pd, off);
                    ps += __shfl_xor(ps, off);
                }
                if (lm == 0 && valid) {
                    atomicAdd(dsc + m, pd);
                    atomicAdd(ssc + m, ps);
                }
            }
        }
    }
}

// ============ fused per-node: softmax + branchless 4-edge-parallel gather + LN ====
// pass 1: logits -> es LDS (+srcoff byte offsets), wave max.
// pass 1.5: es -> w=exp(e-m) in LDS, zero-pad to x8, ssum.
// pass 2: branchless gather: 8 edges/iter, 16 lanes x 16B rows, 16 cvt+fma.
__global__ __launch_bounds__(256) void k_fused(
        const int* __restrict__ offsets, const int* __restrict__ counts,
        const uint2* __restrict__ meta,
        const float* __restrict__ dsc, const float* __restrict__ ssc,
        const float* __restrict__ rel_l,
        const unsigned short* __restrict__ hm,
        const unsigned short* __restrict__ h_in_bf,
        const float* __restrict__ bias_l, const float* __restrict__ g,
        const float* __restrict__ b,
        float* __restrict__ h_out_f32, unsigned short* __restrict__ h_out_bf) {
    __shared__ float rel_s[NR];
    __shared__ float es[4][DCAP];
    __shared__ unsigned srcoff[4][DCAP];
    if (threadIdx.x < NR) rel_s[threadIdx.x] = rel_l[threadIdx.x];
    __syncthreads();

    const int wave = threadIdx.x >> 6, lane = threadIdx.x & 63;
    const int sub = lane & 15, grp = lane >> 4;
    const int d = blockIdx.x * 4 + wave;   // grid exact: 12500*4 == 50000

    const int start = offsets[d];
    const int deg = counts[d];
    const float dsc_d = dsc[d];
    const int degc = deg < DCAP ? deg : DCAP;
    const int degp = (degc + 7) & ~7;

    // pass 1: logits once per edge -> LDS; wave max
    float m_l = -1e30f;
    for (int j = lane; j < deg; j += 64) {
        uint2 mv = meta[start + j];
        unsigned s = mv.x & 0xffff;
        float e = dsc_d + ssc[s] + rel_s[(mv.x >> 16) & 7];
        e = (e > 0.f ? e : 0.2f * e) + __uint_as_float(mv.y);
        if (j < DCAP) { es[wave][j] = e; srcoff[wave][j] = s * (H_DIM * 2); }
        m_l = fmaxf(m_l, e);
    }
    float m = m_l;
    for (int off = 32; off; off >>= 1) m = fmaxf(m, __shfl_xor(m, off));

    // pass 1.5: es -> w in place (same lane wrote these slots); pad to x8; ssum
    float s_l = 0.f;
    for (int j = lane; j < degp; j += 64) {
        float w = 0.f;
        if (j < degc) w = __expf(es[wave][j] - m);
        else srcoff[wave][j] = 0;
        es[wave][j] = w;
        s_l += w;
    }
    if (deg > DCAP) {      // never in practice (max deg ~45); uniform branch
        for (int j = DCAP + lane; j < deg; j += 64) {
            uint2 mv = meta[start + j];
            float e = dsc_d + ssc[mv.x & 0xffff] + rel_s[(mv.x >> 16) & 7];
            e = (e > 0.f ? e : 0.2f * e) + __uint_as_float(mv.y);
            s_l += __expf(e - m);
        }
    }
    float ssum = s_l;
    for (int off = 32; off; off >>= 1) ssum += __shfl_xor(ssum, off);

    __syncthreads();   // es/srcoff cross-lane visibility

    // pass 2: branchless 8-edges-per-iter gather
    float a0 = 0.f, a1 = 0.f, a2 = 0.f, a3 = 0.f,
          a4 = 0.f, a5 = 0.f, a6 = 0.f, a7 = 0.f;
    const char* hmp = (const char*)hm;
    for (int k0 = 0; k0 < degp; k0 += 8) {
        int ka = k0 + grp, kb = ka + 4;
        float wa = es[wave][ka];  unsigned oa = srcoff[wave][ka];
        float wb = es[wave][kb];  unsigned ob = srcoff[wave][kb];
        uint4 ra = *(const uint4*)(hmp + oa + sub * 16);
        uint4 rb = *(const uint4*)(hmp + ob + sub * 16);
        a0 += wa * bf_lo(ra.x) + wb * bf_lo(rb.x);
        a1 += wa * bf_hi(ra.x) + wb * bf_hi(rb.x);
        a2 += wa * bf_lo(ra.y) + wb * bf_lo(rb.y);
        a3 += wa * bf_hi(ra.y) + wb * bf_hi(rb.y);
        a4 += wa * bf_lo(ra.z) + wb * bf_lo(rb.z);
        a5 += wa * bf_hi(ra.z) + wb * bf_hi(rb.z);
        a6 += wa * bf_lo(ra.w) + wb * bf_lo(rb.w);
        a7 += wa * bf_hi(ra.w) + wb * bf_hi(rb.w);
    }
    if (deg > DCAP) {      // never in practice
        for (int k = DCAP + grp; k < deg; k += 4) {
            uint2 mv = meta[start + k];
            unsigned s = mv.x & 0xffff;
            float e = dsc_d + ssc[s] + rel_s[(mv.x >> 16) & 7];
            e = (e > 0.f ? e : 0.2f * e) + __uint_as_float(mv.y);
            float w = __expf(e - m);
            uint4 rv = *(const uint4*)(hmp + s * (H_DIM * 2) + sub * 16);
            a0 += w * bf_lo(rv.x); a1 += w * bf_hi(rv.x);
            a2 += w * bf_lo(rv.y); a3 += w * bf_hi(rv.y);
            a4 += w * bf_lo(rv.z); a5 += w * bf_hi(rv.z);
            a6 += w * bf_lo(rv.w); a7 += w * bf_hi(rv.w);
        }
    }
    // merge the 4 edge-groups
    a0 += __shfl_xor(a0, 16); a1 += __shfl_xor(a1, 16);
    a2 += __shfl_xor(a2, 16); a3 += __shfl_xor(a3, 16);
    a4 += __shfl_xor(a4, 16); a5 += __shfl_xor(a5, 16);
    a6 += __shfl_xor(a6, 16); a7 += __shfl_xor(a7, 16);
    a0 += __shfl_xor(a0, 32); a1 += __shfl_xor(a1, 32);
    a2 += __shfl_xor(a2, 32); a3 += __shfl_xor(a3, 32);
    a4 += __shfl_xor(a4, 32); a5 += __shfl_xor(a5, 32);
    a6 += __shfl_xor(a6, 32); a7 += __shfl_xor(a7, 32);

    const float inv = (deg > 0) ? 1.f / ssum : 0.f;

    // residual (bf16) + bias + relu on channels sub*8 .. sub*8+7
    uint4 hv = *(const uint4*)(h_in_bf + (size_t)d * H_DIM + sub * 8);
    float4 b0 = *(const float4*)(bias_l + sub * 8);
    float4 b1 = *(const float4*)(bias_l + sub * 8 + 4);
    float v0 = bf_lo(hv.x) + fmaxf(a0 * inv + b0.x, 0.f);
    float v1 = bf_hi(hv.x) + fmaxf(a1 * inv + b0.y, 0.f);
    float v2 = bf_lo(hv.y) + fmaxf(a2 * inv + b0.z, 0.f);
    float v3 = bf_hi(hv.y) + fmaxf(a3 * inv + b0.w, 0.f);
    float v4 = bf_lo(hv.z) + fmaxf(a4 * inv + b1.x, 0.f);
    float v5 = bf_hi(hv.z) + fmaxf(a5 * inv + b1.y, 0.f);
    float v6 = bf_lo(hv.w) + fmaxf(a6 * inv + b1.z, 0.f);
    float v7 = bf_hi(hv.w) + fmaxf(a7 * inv + b1.w, 0.f);

    // layernorm: lanes hold 8 channels; 4 groups are duplicates -> divide by 512
    float sum = v0 + v1 + v2 + v3 + v4 + v5 + v6 + v7;
    for (int off = 32; off; off >>= 1) sum += __shfl_xor(sum, off);
    float mu = sum * (1.f / (H_DIM * 4));
    float d0 = v0 - mu, d1 = v1 - mu, d2 = v2 - mu, d3 = v3 - mu;
    float d4 = v4 - mu, d5 = v5 - mu, d6 = v6 - mu, d7 = v7 - mu;
    float vs = d0 * d0 + d1 * d1 + d2 * d2 + d3 * d3 +
               d4 * d4 + d5 * d5 + d6 * d6 + d7 * d7;
    for (int off = 32; off; off >>= 1) vs += __shfl_xor(vs, off);
    float invstd = rsqrtf(vs * (1.f / (H_DIM * 4)) + LN_EPS);

    float4 g0 = *(const float4*)(g + sub * 8);
    float4 g1 = *(const float4*)(g + sub * 8 + 4);
    float4 bb0 = *(const float4*)(b + sub * 8);
    float4 bb1 = *(const float4*)(b + sub * 8 + 4);
    float o0 = d0 * invstd * g0.x + bb0.x;
    float o1 = d1 * invstd * g0.y + bb0.y;
    float o2 = d2 * invstd * g0.z + bb0.z;
    float o3 = d3 * invstd * g0.w + bb0.w;
    float o4 = d4 * invstd * g1.x + bb1.x;
    float o5 = d5 * invstd * g1.y + bb1.y;
    float o6 = d6 * invstd * g1.z + bb1.z;
    float o7 = d7 * invstd * g1.w + bb1.w;

    if (grp == 0) {   // groups hold identical results; one group stores the row
        if (h_out_f32) {
            float* p = h_out_f32 + (size_t)d * H_DIM + sub * 8;
            *(float4*)p = make_float4(o0, o1, o2, o3);
            *(float4*)(p + 4) = make_float4(o4, o5, o6, o7);
        }
        if (h_out_bf) {
            uint4 pk;
            pk.x = (unsigned)f2bf(o0) | ((unsigned)f2bf(o1) << 16);
            pk.y = (unsigned)f2bf(o2) | ((unsigned)f2bf(o3) << 16);
            pk.z = (unsigned)f2bf(o4) | ((unsigned)f2bf(o5) << 16);
            pk.w = (unsigned)f2bf(o6) | ((unsigned)f2bf(o7) << 16);
            *(uint4*)(h_out_bf + (size_t)d * H_DIM + sub * 8) = pk;
        }
    }
}

extern "C" void kernel_launch(void* const* d_in, const int* in_sizes, int n_in,
                              void* d_out, int out_size, void* d_ws, size_t ws_size,
                              hipStream_t stream) {
    const float* x         = (const float*)d_in[0];
    const int*   edge_index= (const int*)d_in[1];
    const int*   edge_type = (const int*)d_in[2];
    const float* edge_attr = (const float*)d_in[3];
    const float* W_in      = (const float*)d_in[4];
    const float* b_in      = (const float*)d_in[5];
    const float* W_msg     = (const float*)d_in[6];
    const float* rel_emb   = (const float*)d_in[7];
    const float* W_rel     = (const float*)d_in[8];
    const float* att_vec   = (const float*)d_in[9];
    const float* bias      = (const float*)d_in[10];
    const float* ln_g      = (const float*)d_in[11];
    const float* ln_b      = (const float*)d_in[12];
    float* out = (float*)d_out;

    // workspace layout (~37 MB)
    char* w = (char*)d_ws;
    unsigned short* h_bf = (unsigned short*)w; w += (size_t)N_NODES * H_DIM * 2; // 12.8
    unsigned short* hm_b = (unsigned short*)w; w += (size_t)N_NODES * H_DIM * 2; // 12.8
    uint2* meta_sorted = (uint2*)w; w += (size_t)NE * 8;               //  6.4 MB
    int*   rank       = (int*)w;   w += (size_t)NE * 4;                //  3.2 MB
    int*   counts     = (int*)w;   w += (size_t)N_NODES * 4;
    int*   offsets    = (int*)w;   w += (size_t)N_NODES * 4;
    float* dsc        = (float*)w; w += (size_t)NL * N_NODES * 4;
    float* ssc        = (float*)w; w += (size_t)NL * N_NODES * 4;
    unsigned short* Wt_in  = (unsigned short*)w; w += (size_t)H_DIM * IN_DIM * 2;
    unsigned short* Wt_msg = (unsigned short*)w; w += (size_t)NL * H_DIM * H_DIM * 2;
    float* rel_score  = (float*)w; w += 64 * 4;
    int*   bsum       = (int*)w;   w += 64 * 4;
    int*   bbase      = (int*)w;   w += 64 * 4;

    const int* srcv = edge_index;
    const int* dstv = edge_index + NE;

    // ---- setup (zeros counts/dsc/ssc, cvt weights, rel_score) then CSR build
    k_setup<<<(NL * N_NODES + 255) / 256, 256, 0, stream>>>(
        W_in, W_msg, rel_emb, W_rel, att_vec, Wt_in, Wt_msg, dsc, ssc, counts,
        rel_score);
    k_count<<<(NE + 255) / 256, 256, 0, stream>>>(dstv, counts, rank);
    k_scan1<<<NB_SCAN, 256, 0, stream>>>(counts, bsum);
    k_scan2<<<1, 64, 0, stream>>>(bsum, bbase);
    k_scan3<<<NB_SCAN, 256, 0, stream>>>(counts, bbase, offsets);
    k_perm<<<(NE + 255) / 256, 256, 0, stream>>>(srcv, dstv, edge_type, edge_attr,
                                                 offsets, rank, meta_sorted);

    const int GB = (N_NODES + 127) / 128;   // 391
    k_gemm_mfma<IN_DIM, false, true, false><<<GB, 256, 0, stream>>>(
        x, Wt_in, b_in, h_bf, N_NODES, nullptr, nullptr, nullptr);

    for (int l = 0; l < NL; ++l) {
        k_gemm_mfma<H_DIM, true, false, true><<<GB, 256, 0, stream>>>(
            h_bf, Wt_msg + (size_t)l * H_DIM * H_DIM, nullptr, hm_b, N_NODES,
            att_vec + (size_t)l * 3 * H_DIM, dsc + (size_t)l * N_NODES,
            ssc + (size_t)l * N_NODES);
        k_fused<<<N_NODES / 4, 256, 0, stream>>>(
            offsets, counts, meta_sorted,
            dsc + (size_t)l * N_NODES, ssc + (size_t)l * N_NODES,
            rel_score + l * NR, hm_b, h_bf,
            bias + (size_t)l * H_DIM, ln_g + (size_t)l * H_DIM,
            ln_b + (size_t)l * H_DIM,
            (l == NL - 1) ? out : nullptr,
            (l == NL - 1) ? nullptr : h_bf);
    }
}